// Round 1
// baseline (11201.837 us; speedup 1.0000x reference)
//
#include <hip/hip_runtime.h>

// ---------------------------------------------------------------------------
// GLOM forward, f32 correctness-first baseline.
// B=8, H=W=32, P=1024, N=8192 tokens, E=512, LF=10 (4LF=40), FAN=552.
// ---------------------------------------------------------------------------

#define PI_F 3.14159265358979323846f

static constexpr int   BB    = 8;
static constexpr int   PP    = 1024;      // H*W
static constexpr int   NT    = 8192;      // B*P
static constexpr int   EE    = 512;
static constexpr int   FANC  = 552;
static constexpr float BETA_F = 0.001f;
static constexpr float EPS_F  = 1e-5f;
static constexpr size_t NEs = (size_t)NT * EE;   // 4,194,304 floats
static constexpr size_t PEs = (size_t)PP * EE;   //   524,288 floats

// ---------------- positional-encoding table [P,40] --------------------------
__global__ void k_locb(float* __restrict__ locb) {
  int q = blockIdx.x * blockDim.x + threadIdx.x;
  if (q >= PP) return;
  int h = q >> 5, w = q & 31;
  float ph = 2.f * (float)h / 32.f - 1.f;
  float pw = 2.f * (float)w / 32.f - 1.f;
  float* d = locb + (size_t)q * 40;
#pragma unroll
  for (int j = 0; j < 10; ++j) {
    float f = (float)(1 << j) * PI_F;
    float ah = f * ph, aw = f * pw;
    d[2*j]     = sinf(ah); d[2*j+1]  = cosf(ah);
    d[20+2*j]  = sinf(aw); d[21+2*j] = cosf(aw);
  }
}

// ------------- loc contribution + bias: loc_bu/loc_td [5][P][E] -------------
__global__ __launch_bounds__(256) void k_loclin(const float* __restrict__ locb,
    const float* __restrict__ buw, const float* __restrict__ bub,
    const float* __restrict__ tdw, const float* __restrict__ tdb,
    float* __restrict__ lbu, float* __restrict__ ltd) {
  int q = blockIdx.x;           // 0..1023
  int m = blockIdx.y;           // 0..9 : 0-4 bu levels, 5-9 td levels
  __shared__ float lb[40];
  int t = threadIdx.x;
  if (t < 40) lb[t] = locb[(size_t)q*40 + t];
  __syncthreads();
  int l = (m < 5) ? m : m - 5;
  const float* W    = ((m < 5) ? buw : tdw) + (size_t)l*EE*FANC;
  const float* bias = ((m < 5) ? bub : tdb) + (size_t)l*EE;
  float* dst = ((m < 5) ? lbu : ltd) + (size_t)l*PEs + (size_t)q*EE;
  for (int e = t; e < EE; e += 256) {
    const float* wr = W + (size_t)e*FANC + EE;   // cols 512..551
    float acc = bias[e];
#pragma unroll
    for (int f = 0; f < 40; ++f) acc += lb[f]*wr[f];
    dst[e] = acc;
  }
}

// ---------------- patch conv as GEMM: z[n,e], 8 tokens / block --------------
__global__ __launch_bounds__(256) void k_conv(const float* __restrict__ x,
    const float* __restrict__ cw, const float* __restrict__ cb,
    float* __restrict__ z) {
  __shared__ float patch[8][192];
  int t = threadIdx.x;
  int n0 = blockIdx.x * 8;
  for (int i = t; i < 8*192; i += 256) {
    int tok = i / 192, f = i - tok*192;
    int n = n0 + tok;
    int b = n >> 10, hw = n & 1023, h = hw >> 5, w = hw & 31;
    int c = f >> 6, r = f & 63, kh = r >> 3, kw = r & 7;
    patch[tok][f] = x[((size_t)(b*3 + c)*256 + (size_t)(h*8 + kh))*256 + (w*8 + kw)];
  }
  __syncthreads();
  for (int u = 0; u < 2; ++u) {
    int e = t + 256*u;
    float acc[8];
    float bias = cb[e];
#pragma unroll
    for (int tok = 0; tok < 8; ++tok) acc[tok] = bias;
    const float4* wr = (const float4*)(cw + (size_t)e*192);
    for (int f4 = 0; f4 < 48; ++f4) {
      float4 wv = wr[f4];
#pragma unroll
      for (int tok = 0; tok < 8; ++tok) {
        float4 pv = ((const float4*)patch[tok])[f4];
        acc[tok] += wv.x*pv.x + wv.y*pv.y + wv.z*pv.z + wv.w*pv.w;
      }
    }
    for (int tok = 0; tok < 8; ++tok) z[(size_t)(n0+tok)*EE + e] = acc[tok];
  }
}

// ---------------- BatchNorm (training-mode batch stats) ---------------------
__global__ __launch_bounds__(512) void k_bnstats(const float* __restrict__ X,
                                                 float* __restrict__ stats) {
  int t = threadIdx.x;            // channel
  int r0 = blockIdx.x * 32;       // 256 blocks * 32 rows = 8192
  float s = 0.f, sq = 0.f;
  for (int r = 0; r < 32; ++r) {
    float v = X[(size_t)(r0+r)*EE + t];
    s += v; sq += v*v;
  }
  atomicAdd(&stats[t], s);
  atomicAdd(&stats[EE+t], sq);
}

__global__ void k_bnfin(const float* __restrict__ stats, const float* __restrict__ g,
                        const float* __restrict__ bta, float* __restrict__ ss) {
  int t = threadIdx.x;            // 512
  float mean = stats[t] * (1.f/8192.f);
  float var  = stats[EE+t] * (1.f/8192.f) - mean*mean;
  var = fmaxf(var, 0.f);
  float sc = g[t] * rsqrtf(var + EPS_F);
  ss[t]    = sc;
  ss[EE+t] = bta[t] - mean*sc;
}

__global__ __launch_bounds__(256) void k_bnapply(float* __restrict__ X,
                                                 const float* __restrict__ ss) {
  size_t i = (size_t)blockIdx.x*256 + threadIdx.x;   // NE/4 float4s
  float4 v = ((float4*)X)[i];
  int c = (int)((i & 127) << 2);
  v.x = v.x*ss[c]   + ss[EE+c];
  v.y = v.y*ss[c+1] + ss[EE+c+1];
  v.z = v.z*ss[c+2] + ss[EE+c+2];
  v.w = v.w*ss[c+3] + ss[EE+c+3];
  ((float4*)X)[i] = v;
}

// ---------------- attention numerator + per-(b,q) partial sums --------------
// grid (64 q-tiles, 8 batches), 256 threads. num[n,e], srow[b,q].
__global__ __launch_bounds__(256) void k_attn(const float* __restrict__ X,
    float* __restrict__ num, float* __restrict__ srow) {
  int qt = blockIdx.x;
  int b  = blockIdx.y;
  const float* Eb = X + (size_t)b * PP * EE;
  __shared__ float qs[16][520];    // Q tile, full K-depth
  __shared__ float ks[64][72];     // K chunk (64 keys x 64 depth), pad 72 (2-way max)
  __shared__ float sxs[16][72];    // exp(beta*S) tile
  int t = threadIdx.x;
  int q0 = qt * 16;
  for (int i = t; i < 16*128; i += 256) {
    int q = i >> 7, c4 = i & 127;
    ((float4*)&qs[q][0])[c4] = ((const float4*)(Eb + (size_t)(q0+q)*EE))[c4];
  }
  float4 acc[8];
#pragma unroll
  for (int m = 0; m < 8; ++m) acc[m] = make_float4(0.f,0.f,0.f,0.f);
  float srAcc = 0.f;
  int tq = t >> 5, tk = t & 31;    // score microtile owner (2q x 2k)
  int qb = t >> 4, g  = t & 15;    // numerator owner (1q x 128 float4 slice)
  for (int kt = 0; kt < 16; ++kt) {
    int k0 = kt * 64;
    float s00 = 0.f, s01 = 0.f, s10 = 0.f, s11 = 0.f;
    for (int c0 = 0; c0 < EE; c0 += 64) {
      __syncthreads();
      for (int i = t; i < 64*16; i += 256) {
        int k = i >> 4, c4 = i & 15;
        ((float4*)&ks[k][0])[c4] = ((const float4*)(Eb + (size_t)(k0+k)*EE + c0))[c4];
      }
      __syncthreads();
#pragma unroll 8
      for (int c = 0; c < 64; c += 2) {
        float2 qa = *(const float2*)&qs[2*tq  ][c0+c];
        float2 qc = *(const float2*)&qs[2*tq+1][c0+c];
        float2 ka = *(const float2*)&ks[2*tk  ][c];
        float2 kb = *(const float2*)&ks[2*tk+1][c];
        s00 += qa.x*ka.x + qa.y*ka.y;
        s01 += qa.x*kb.x + qa.y*kb.y;
        s10 += qc.x*ka.x + qc.y*ka.y;
        s11 += qc.x*kb.x + qc.y*kb.y;
      }
    }
    __syncthreads();
    sxs[2*tq  ][2*tk  ] = expf(BETA_F*s00);
    sxs[2*tq  ][2*tk+1] = expf(BETA_F*s01);
    sxs[2*tq+1][2*tk  ] = expf(BETA_F*s10);
    sxs[2*tq+1][2*tk+1] = expf(BETA_F*s11);
    __syncthreads();
    if (t < 16) {
      float ssum = 0.f;
#pragma unroll
      for (int k = 0; k < 64; ++k) ssum += sxs[t][k];
      srAcc += ssum;
    }
    const float* sr = &sxs[qb][0];
    const float* vbase = Eb + (size_t)k0*EE;
    for (int k = 0; k < 64; ++k) {
      float p = sr[k];
      const float4* vr = (const float4*)(vbase + (size_t)k*EE);
#pragma unroll
      for (int m = 0; m < 8; ++m) {
        float4 v = vr[g + 16*m];
        acc[m].x += p*v.x; acc[m].y += p*v.y; acc[m].z += p*v.z; acc[m].w += p*v.w;
      }
    }
  }
  float4* nr = (float4*)(num + (size_t)(b*PP + q0 + qb)*EE);
#pragma unroll
  for (int m = 0; m < 8; ++m) nr[g + 16*m] = acc[m];
  if (t < 16) srow[(size_t)b*PP + q0 + t] = srAcc;
}

// denom[q] = sum_b srow[b][q]   (reference sums exp over batch AND keys)
__global__ void k_denom(const float* __restrict__ srow, float* __restrict__ denom) {
  int q = blockIdx.x*blockDim.x + threadIdx.x;
  if (q >= PP) return;
  float s = 0.f;
#pragma unroll
  for (int b = 0; b < 8; ++b) s += srow[(size_t)b*PP + q];
  denom[q] = s;
}

// --------- fused level update: w1*prevBN + w2*bu + w3*td + w4*avg -----------
// 64x64 tile, 4x4 microtile, K=512 against W[:, :512] (row stride FAN).
__global__ __launch_bounds__(256) void k_update(const float* __restrict__ Xbn,
    const float* __restrict__ num, const float* __restrict__ denom,
    const float* __restrict__ Abu, const float* __restrict__ Wbu, const float* __restrict__ Lbu,
    const float* __restrict__ Atd, const float* __restrict__ Wtd, const float* __restrict__ Ltd,
    const float* __restrict__ w1p, const float* __restrict__ w2p,
    const float* __restrict__ w3p, const float* __restrict__ w4p,
    float* __restrict__ O) {
  __shared__ float As[64][20];
  __shared__ float Ws[64][20];
  int t = threadIdx.x;
  int n0 = blockIdx.x * 64, e0 = blockIdx.y * 64;
  int tn = t >> 4, te = t & 15;
  int sr = t >> 2, sc4 = t & 3;
  float abu[4][4] = {{0.f}}, atd[4][4] = {{0.f}};
  if (Abu) {
    for (int c0 = 0; c0 < EE; c0 += 16) {
      __syncthreads();
      ((float4*)As[sr])[sc4] = ((const float4*)(Abu + (size_t)(n0+sr)*EE + c0))[sc4];
      ((float4*)Ws[sr])[sc4] = ((const float4*)(Wbu + (size_t)(e0+sr)*FANC + c0))[sc4];
      __syncthreads();
#pragma unroll
      for (int c = 0; c < 16; c += 2) {
        float2 av[4], wv[4];
#pragma unroll
        for (int i = 0; i < 4; ++i) av[i] = *(const float2*)&As[tn*4+i][c];
#pragma unroll
        for (int j = 0; j < 4; ++j) wv[j] = *(const float2*)&Ws[te*4+j][c];
#pragma unroll
        for (int i = 0; i < 4; ++i)
#pragma unroll
          for (int j = 0; j < 4; ++j)
            abu[i][j] += av[i].x*wv[j].x + av[i].y*wv[j].y;
      }
    }
  }
  if (Atd) {
    for (int c0 = 0; c0 < EE; c0 += 16) {
      __syncthreads();
      ((float4*)As[sr])[sc4] = ((const float4*)(Atd + (size_t)(n0+sr)*EE + c0))[sc4];
      ((float4*)Ws[sr])[sc4] = ((const float4*)(Wtd + (size_t)(e0+sr)*FANC + c0))[sc4];
      __syncthreads();
#pragma unroll
      for (int c = 0; c < 16; c += 2) {
        float2 av[4], wv[4];
#pragma unroll
        for (int i = 0; i < 4; ++i) av[i] = *(const float2*)&As[tn*4+i][c];
#pragma unroll
        for (int j = 0; j < 4; ++j) wv[j] = *(const float2*)&Ws[te*4+j][c];
#pragma unroll
        for (int i = 0; i < 4; ++i)
#pragma unroll
          for (int j = 0; j < 4; ++j)
            atd[i][j] += av[i].x*wv[j].x + av[i].y*wv[j].y;
      }
    }
  }
  float w1 = *w1p, w2 = *w2p, w3 = *w3p, w4 = *w4p;
#pragma unroll
  for (int i = 0; i < 4; ++i) {
    int n = n0 + tn*4 + i;
    int hw = n & 1023;
    float rd = 1.f / denom[hw];
#pragma unroll
    for (int j = 0; j < 4; ++j) {
      int e = e0 + te*4 + j;
      size_t idx = (size_t)n*EE + e;
      float v = w1*Xbn[idx] + w4*num[idx]*rd;
      if (Abu) v += w2*(abu[i][j] + Lbu[(size_t)hw*EE + e]);
      if (Atd) v += w3*(atd[i][j] + Ltd[(size_t)hw*EE + e]);
      O[idx] = v;
    }
  }
}

// ---------------- final transpose: ws slots [l][n][e] -> out [b][e][hw][5] --
__global__ __launch_bounds__(256) void k_transpose(const float* __restrict__ ws,
                                                   float* __restrict__ out) {
  __shared__ float tile[5][32][33];
  int t = threadIdx.x;
  int hw0 = blockIdx.x * 32, e0 = blockIdx.y * 32, b = blockIdx.z;
  int tr = t >> 5, tc = t & 31;
#pragma unroll
  for (int l = 0; l < 5; ++l) {
    const float* src = ws + (size_t)l*NEs + ((size_t)(b*PP + hw0))*EE + e0;
    for (int p = 0; p < 4; ++p)
      tile[l][tr + 8*p][tc] = src[(size_t)(tr + 8*p)*EE + tc];
  }
  __syncthreads();
  for (int p = 0; p < 4; ++p) {
    int e = tr + 8*p;
    float* dst = out + (((size_t)(b*EE + e0 + e))*PP + (size_t)(hw0 + tc))*5;
#pragma unroll
    for (int l = 0; l < 5; ++l) dst[l] = tile[l][tc][e];
  }
}

// ---------------------------------------------------------------------------
extern "C" void kernel_launch(void* const* d_in, const int* in_sizes, int n_in,
                              void* d_out, int out_size, void* d_ws, size_t ws_size,
                              hipStream_t stream) {
  const float* x     = (const float*)d_in[0];
  const float* convw = (const float*)d_in[1];
  const float* convb = (const float*)d_in[2];
  const float* bu_w  = (const float*)d_in[3];
  const float* bu_b  = (const float*)d_in[4];
  const float* td_w  = (const float*)d_in[5];
  const float* td_b  = (const float*)d_in[6];
  const float* bn_g  = (const float*)d_in[7];
  const float* bn_b  = (const float*)d_in[8];
  const float* w1 = (const float*)d_in[9];
  const float* w2 = (const float*)d_in[10];
  const float* w3 = (const float*)d_in[11];
  const float* w4 = (const float*)d_in[12];
  float* out = (float*)d_out;
  float* ws  = (float*)d_ws;

  // ws layout (floats): 5 slots | num | loc_bu[5] | loc_td[5] | locb | stats | ss | srow | denom
  float* slots = ws;                       // 5*NE   (cycle-0 prev, cycle-1 new)
  float* num   = ws + 5*NEs;               // NE
  float* locbu = ws + 6*NEs;               // 5*PE
  float* loctd = locbu + 5*PEs;            // 5*PE
  float* locb  = loctd + 5*PEs;            // 40960
  float* stats = locb + 40960;             // 1024
  float* ssbuf = stats + 1024;             // 1024
  float* srow  = ssbuf + 1024;             // 8192
  float* denom = srow + 8192;              // 1024
  // total ~30.46M floats (~122 MB)

  k_locb<<<4, 256, 0, stream>>>(locb);
  k_loclin<<<dim3(1024, 10), 256, 0, stream>>>(locb, bu_w, bu_b, td_w, td_b, locbu, loctd);
  k_conv<<<1024, 256, 0, stream>>>(x, convw, convb, slots);
  hipMemsetAsync(slots + NEs, 0, 4*NEs*sizeof(float), stream);   // levels 1..4 = 0

  for (int cyc = 0; cyc < 2; ++cyc) {
    for (int l = 0; l < 5; ++l) {
      // prev of this cycle lives in ws slots (cyc 0) or d_out slots (cyc 1)
      float* X = (cyc == 0) ? (slots + (size_t)l*NEs) : (out + (size_t)l*NEs);
      hipMemsetAsync(stats, 0, 1024*sizeof(float), stream);
      k_bnstats<<<256, 512, 0, stream>>>(X, stats);
      k_bnfin<<<1, 512, 0, stream>>>(stats, bn_g + (size_t)l*EE, bn_b + (size_t)l*EE, ssbuf);
      k_bnapply<<<4096, 256, 0, stream>>>(X, ssbuf);
      k_attn<<<dim3(64, 8), 256, 0, stream>>>(X, num, srow);
      k_denom<<<4, 256, 0, stream>>>(srow, denom);
      const float* Abu = nullptr;
      const float* Atd = nullptr;
      if (l > 0) Abu = (cyc == 0) ? (slots + (size_t)(l-1)*NEs) : (out + (size_t)(l-1)*NEs); // post-BN
      if (l < 4) Atd = (cyc == 0) ? (slots + (size_t)(l+1)*NEs) : (out + (size_t)(l+1)*NEs); // pre-BN
      float* O = (cyc == 0) ? (out + (size_t)l*NEs) : (slots + (size_t)l*NEs);
      k_update<<<dim3(128, 8), 256, 0, stream>>>(X, num, denom,
          Abu, bu_w + (size_t)l*EE*FANC, locbu + (size_t)l*PEs,
          Atd, td_w + (size_t)l*EE*FANC, loctd + (size_t)l*PEs,
          w1, w2, w3, w4, O);
    }
  }
  // emb (cycle-1 new) is in ws slots -> transpose into final output layout
  k_transpose<<<dim3(32, 16, 8), 256, 0, stream>>>(slots, out);
}

// Round 2
// 5404.618 us; speedup vs baseline: 2.0726x; 2.0726x over previous
//
#include <hip/hip_runtime.h>

// ---------------------------------------------------------------------------
// GLOM forward. Round 2: attention on bf16 MFMA (16x16x32).
// B=8, H=W=32, P=1024, N=8192 tokens, E=512, LF=10 (4LF=40), FAN=552.
// ---------------------------------------------------------------------------

#define PI_F 3.14159265358979323846f

static constexpr int   BB    = 8;
static constexpr int   PP    = 1024;      // H*W
static constexpr int   NT    = 8192;      // B*P
static constexpr int   EE    = 512;
static constexpr int   FANC  = 552;
static constexpr float BETA_F = 0.001f;
static constexpr float EPS_F  = 1e-5f;
static constexpr size_t NEs = (size_t)NT * EE;   // 4,194,304
static constexpr size_t PEs = (size_t)PP * EE;   //   524,288

typedef __attribute__((ext_vector_type(8))) short short8v;  // 8 bf16 (4 VGPRs)
typedef __attribute__((ext_vector_type(4))) float f32x4;

__device__ __forceinline__ unsigned short f2bf(float x) {
  unsigned u = __float_as_uint(x);
  unsigned r = ((u >> 16) & 1u) + 0x7fffu;   // RNE
  return (unsigned short)((u + r) >> 16);
}

// ---------------- positional-encoding table [P,40] --------------------------
__global__ void k_locb(float* __restrict__ locb) {
  int q = blockIdx.x * blockDim.x + threadIdx.x;
  if (q >= PP) return;
  int h = q >> 5, w = q & 31;
  float ph = 2.f * (float)h / 32.f - 1.f;
  float pw = 2.f * (float)w / 32.f - 1.f;
  float* d = locb + (size_t)q * 40;
#pragma unroll
  for (int j = 0; j < 10; ++j) {
    float f = (float)(1 << j) * PI_F;
    float ah = f * ph, aw = f * pw;
    d[2*j]     = sinf(ah); d[2*j+1]  = cosf(ah);
    d[20+2*j]  = sinf(aw); d[21+2*j] = cosf(aw);
  }
}

// ------------- loc contribution + bias: loc_bu/loc_td [5][P][E] -------------
__global__ __launch_bounds__(256) void k_loclin(const float* __restrict__ locb,
    const float* __restrict__ buw, const float* __restrict__ bub,
    const float* __restrict__ tdw, const float* __restrict__ tdb,
    float* __restrict__ lbu, float* __restrict__ ltd) {
  int q = blockIdx.x;           // 0..1023
  int m = blockIdx.y;           // 0..9 : 0-4 bu levels, 5-9 td levels
  __shared__ float lb[40];
  int t = threadIdx.x;
  if (t < 40) lb[t] = locb[(size_t)q*40 + t];
  __syncthreads();
  int l = (m < 5) ? m : m - 5;
  const float* W    = ((m < 5) ? buw : tdw) + (size_t)l*EE*FANC;
  const float* bias = ((m < 5) ? bub : tdb) + (size_t)l*EE;
  float* dst = ((m < 5) ? lbu : ltd) + (size_t)l*PEs + (size_t)q*EE;
  for (int e = t; e < EE; e += 256) {
    const float* wr = W + (size_t)e*FANC + EE;   // cols 512..551
    float acc = bias[e];
#pragma unroll
    for (int f = 0; f < 40; ++f) acc += lb[f]*wr[f];
    dst[e] = acc;
  }
}

// ---------------- patch conv as GEMM: z[n,e], 8 tokens / block --------------
__global__ __launch_bounds__(256) void k_conv(const float* __restrict__ x,
    const float* __restrict__ cw, const float* __restrict__ cb,
    float* __restrict__ z) {
  __shared__ float patch[8][192];
  int t = threadIdx.x;
  int n0 = blockIdx.x * 8;
  for (int i = t; i < 8*192; i += 256) {
    int tok = i / 192, f = i - tok*192;
    int n = n0 + tok;
    int b = n >> 10, hw = n & 1023, h = hw >> 5, w = hw & 31;
    int c = f >> 6, r = f & 63, kh = r >> 3, kw = r & 7;
    patch[tok][f] = x[((size_t)(b*3 + c)*256 + (size_t)(h*8 + kh))*256 + (w*8 + kw)];
  }
  __syncthreads();
  for (int u = 0; u < 2; ++u) {
    int e = t + 256*u;
    float acc[8];
    float bias = cb[e];
#pragma unroll
    for (int tok = 0; tok < 8; ++tok) acc[tok] = bias;
    const float4* wr = (const float4*)(cw + (size_t)e*192);
    for (int f4 = 0; f4 < 48; ++f4) {
      float4 wv = wr[f4];
#pragma unroll
      for (int tok = 0; tok < 8; ++tok) {
        float4 pv = ((const float4*)patch[tok])[f4];
        acc[tok] += wv.x*pv.x + wv.y*pv.y + wv.z*pv.z + wv.w*pv.w;
      }
    }
    for (int tok = 0; tok < 8; ++tok) z[(size_t)(n0+tok)*EE + e] = acc[tok];
  }
}

// ---------------- BatchNorm (training-mode batch stats) ---------------------
__global__ __launch_bounds__(512) void k_bnstats(const float* __restrict__ X,
                                                 float* __restrict__ stats) {
  int t = threadIdx.x;            // channel
  int r0 = blockIdx.x * 32;       // 256 blocks * 32 rows = 8192
  float s = 0.f, sq = 0.f;
  for (int r = 0; r < 32; ++r) {
    float v = X[(size_t)(r0+r)*EE + t];
    s += v; sq += v*v;
  }
  atomicAdd(&stats[t], s);
  atomicAdd(&stats[EE+t], sq);
}

__global__ void k_bnfin(const float* __restrict__ stats, const float* __restrict__ g,
                        const float* __restrict__ bta, float* __restrict__ ss) {
  int t = threadIdx.x;            // 512
  float mean = stats[t] * (1.f/8192.f);
  float var  = stats[EE+t] * (1.f/8192.f) - mean*mean;
  var = fmaxf(var, 0.f);
  float sc = g[t] * rsqrtf(var + EPS_F);
  ss[t]    = sc;
  ss[EE+t] = bta[t] - mean*sc;
}

__global__ __launch_bounds__(256) void k_bnapply(float* __restrict__ X,
                                                 const float* __restrict__ ss) {
  size_t i = (size_t)blockIdx.x*256 + threadIdx.x;   // NE/4 float4s
  float4 v = ((float4*)X)[i];
  int c = (int)((i & 127) << 2);
  v.x = v.x*ss[c]   + ss[EE+c];
  v.y = v.y*ss[c+1] + ss[EE+c+1];
  v.z = v.z*ss[c+2] + ss[EE+c+2];
  v.w = v.w*ss[c+3] + ss[EE+c+3];
  ((float4*)X)[i] = v;
}

// -------- bf16 conversion + transpose: Xbf [b][p][e], XbfT [b][e][p] --------
__global__ __launch_bounds__(256) void k_tobf(const float* __restrict__ X,
    unsigned short* __restrict__ Xbf, unsigned short* __restrict__ XbfT) {
  __shared__ unsigned short tile[32][34];
  int b = blockIdx.z;
  int p0 = blockIdx.x * 32, e0 = blockIdx.y * 32;
  int tr = threadIdx.x >> 5, tc = threadIdx.x & 31;
#pragma unroll
  for (int i = 0; i < 4; ++i) {
    int p = tr + 8*i;                       // local p row
    size_t idx = (size_t)(b*PP + p0 + p)*EE + e0 + tc;
    unsigned short us = f2bf(X[idx]);
    Xbf[idx] = us;
    tile[p][tc] = us;
  }
  __syncthreads();
#pragma unroll
  for (int i = 0; i < 4; ++i) {
    int e = tr + 8*i;                       // local e row
    XbfT[(size_t)(b*EE + e0 + e)*PP + p0 + tc] = tile[tc][e];
  }
}

// ---------------- MFMA attention: num[n,e] + srow[b,q] ----------------------
// 1 wave / block, 16 queries / wave, full 1024-key loop, full E=512 acc.
__global__ __launch_bounds__(64, 1) void k_attn_mfma(
    const unsigned short* __restrict__ Xbf,   // [8][1024][512]
    const unsigned short* __restrict__ XbfT,  // [8][512][1024]
    float* __restrict__ num,                  // [8192][512]
    float* __restrict__ srow) {               // [8][1024]
  int l  = threadIdx.x;
  int lo = l & 15, g = l >> 4;
  // XCD-chunked swizzle: one batch per XCD (Xbf+XbfT per batch = 2MB < 4MB L2)
  int id  = blockIdx.x;              // 0..511
  int sid = (id & 7) * 64 + (id >> 3);
  int qt  = sid & 63, b = sid >> 6;
  int q0  = qt * 16;

  __shared__ short8v Pv[128];        // 16 rows x 64 keys bf16, swizzled (2KB)
  char* Pb = (char*)Pv;
  int swz_lo = ((lo & 3) << 4) ^ (((lo >> 2) & 3) << 5);

  const unsigned short* qptr = Xbf + ((size_t)(b*PP + q0 + lo)*EE + g*8);
  short8v qf[16];
#pragma unroll
  for (int c = 0; c < 16; ++c) qf[c] = *(const short8v*)(qptr + c*32);

  f32x4 acc[32] = {};
  float srl[4] = {0.f, 0.f, 0.f, 0.f};

  for (int kt = 0; kt < 16; ++kt) {
    // ---- S = Q K^T over 64 keys (4 sub-tiles interleaved) ----
    f32x4 s[4] = {};
    const unsigned short* kb = Xbf + ((size_t)(b*PP + kt*64 + lo)*EE + g*8);
#pragma unroll
    for (int c = 0; c < 16; ++c) {
      short8v k0 = *(const short8v*)(kb + c*32);
      short8v k1 = *(const short8v*)(kb + 16*EE + c*32);
      short8v k2 = *(const short8v*)(kb + 32*EE + c*32);
      short8v k3 = *(const short8v*)(kb + 48*EE + c*32);
      s[0] = __builtin_amdgcn_mfma_f32_16x16x32_bf16(qf[c], k0, s[0], 0, 0, 0);
      s[1] = __builtin_amdgcn_mfma_f32_16x16x32_bf16(qf[c], k1, s[1], 0, 0, 0);
      s[2] = __builtin_amdgcn_mfma_f32_16x16x32_bf16(qf[c], k2, s[2], 0, 0, 0);
      s[3] = __builtin_amdgcn_mfma_f32_16x16x32_bf16(qf[c], k3, s[3], 0, 0, 0);
    }
    // ---- exp, stage P (bf16) in swizzled LDS, accumulate row sums ----
#pragma unroll
    for (int st = 0; st < 4; ++st) {
#pragma unroll
      for (int r = 0; r < 4; ++r) {
        float e = __expf(BETA_F * s[st][r]);
        srl[r] += e;
        int q  = g*4 + r;                                   // C-layout row
        int sw = ((q & 3) << 4) ^ (((q >> 2) & 3) << 5);
        *(unsigned short*)(Pb + q*128 + (((st*16 + lo)*2) ^ sw)) = f2bf(e);
      }
    }
    __syncthreads();
    short8v pa0 = *(const short8v*)(Pb + lo*128 + ((g*16)      ^ swz_lo));
    short8v pa1 = *(const short8v*)(Pb + lo*128 + ((64 + g*16) ^ swz_lo));
    __syncthreads();
    // ---- PV: num += P * V, V read from XbfT (8 consecutive keys / lane) ----
    const unsigned short* vb = XbfT + ((size_t)(b*EE + lo)*PP + kt*64 + g*8);
#pragma unroll
    for (int et = 0; et < 32; ++et) {
      short8v v0 = *(const short8v*)(vb + (size_t)et*16*PP);
      acc[et] = __builtin_amdgcn_mfma_f32_16x16x32_bf16(pa0, v0, acc[et], 0, 0, 0);
    }
#pragma unroll
    for (int et = 0; et < 32; ++et) {
      short8v v1 = *(const short8v*)(vb + (size_t)et*16*PP + 32);
      acc[et] = __builtin_amdgcn_mfma_f32_16x16x32_bf16(pa1, v1, acc[et], 0, 0, 0);
    }
  }

  // ---- write numerator: row = q0 + g*4 + r, col = et*16 + lo ----
  float* np = num + ((size_t)(b*PP + q0 + g*4)*EE + lo);
#pragma unroll
  for (int et = 0; et < 32; ++et)
#pragma unroll
    for (int r = 0; r < 4; ++r)
      np[(size_t)r*EE + et*16] = acc[et][r];

  // ---- per-query exp row-sums (16-lane-group butterfly) ----
#pragma unroll
  for (int r = 0; r < 4; ++r) {
    float v = srl[r];
    v += __shfl_xor(v, 1); v += __shfl_xor(v, 2);
    v += __shfl_xor(v, 4); v += __shfl_xor(v, 8);
    if (lo == 0) srow[(size_t)b*PP + q0 + g*4 + r] = v;
  }
}

// denom[q] = sum_b srow[b][q]   (reference sums exp over batch AND keys)
__global__ void k_denom(const float* __restrict__ srow, float* __restrict__ denom) {
  int q = blockIdx.x*blockDim.x + threadIdx.x;
  if (q >= PP) return;
  float s = 0.f;
#pragma unroll
  for (int b = 0; b < 8; ++b) s += srow[(size_t)b*PP + q];
  denom[q] = s;
}

// --------- fused level update: w1*prevBN + w2*bu + w3*td + w4*avg -----------
__global__ __launch_bounds__(256) void k_update(const float* __restrict__ Xbn,
    const float* __restrict__ num, const float* __restrict__ denom,
    const float* __restrict__ Abu, const float* __restrict__ Wbu, const float* __restrict__ Lbu,
    const float* __restrict__ Atd, const float* __restrict__ Wtd, const float* __restrict__ Ltd,
    const float* __restrict__ w1p, const float* __restrict__ w2p,
    const float* __restrict__ w3p, const float* __restrict__ w4p,
    float* __restrict__ O) {
  __shared__ float As[64][20];
  __shared__ float Ws[64][20];
  int t = threadIdx.x;
  int n0 = blockIdx.x * 64, e0 = blockIdx.y * 64;
  int tn = t >> 4, te = t & 15;
  int sr = t >> 2, sc4 = t & 3;
  float abu[4][4] = {{0.f}}, atd[4][4] = {{0.f}};
  if (Abu) {
    for (int c0 = 0; c0 < EE; c0 += 16) {
      __syncthreads();
      ((float4*)As[sr])[sc4] = ((const float4*)(Abu + (size_t)(n0+sr)*EE + c0))[sc4];
      ((float4*)Ws[sr])[sc4] = ((const float4*)(Wbu + (size_t)(e0+sr)*FANC + c0))[sc4];
      __syncthreads();
#pragma unroll
      for (int c = 0; c < 16; c += 2) {
        float2 av[4], wv[4];
#pragma unroll
        for (int i = 0; i < 4; ++i) av[i] = *(const float2*)&As[tn*4+i][c];
#pragma unroll
        for (int j = 0; j < 4; ++j) wv[j] = *(const float2*)&Ws[te*4+j][c];
#pragma unroll
        for (int i = 0; i < 4; ++i)
#pragma unroll
          for (int j = 0; j < 4; ++j)
            abu[i][j] += av[i].x*wv[j].x + av[i].y*wv[j].y;
      }
    }
  }
  if (Atd) {
    for (int c0 = 0; c0 < EE; c0 += 16) {
      __syncthreads();
      ((float4*)As[sr])[sc4] = ((const float4*)(Atd + (size_t)(n0+sr)*EE + c0))[sc4];
      ((float4*)Ws[sr])[sc4] = ((const float4*)(Wtd + (size_t)(e0+sr)*FANC + c0))[sc4];
      __syncthreads();
#pragma unroll
      for (int c = 0; c < 16; c += 2) {
        float2 av[4], wv[4];
#pragma unroll
        for (int i = 0; i < 4; ++i) av[i] = *(const float2*)&As[tn*4+i][c];
#pragma unroll
        for (int j = 0; j < 4; ++j) wv[j] = *(const float2*)&Ws[te*4+j][c];
#pragma unroll
        for (int i = 0; i < 4; ++i)
#pragma unroll
          for (int j = 0; j < 4; ++j)
            atd[i][j] += av[i].x*wv[j].x + av[i].y*wv[j].y;
      }
    }
  }
  float w1 = *w1p, w2 = *w2p, w3 = *w3p, w4 = *w4p;
#pragma unroll
  for (int i = 0; i < 4; ++i) {
    int n = n0 + tn*4 + i;
    int hw = n & 1023;
    float rd = 1.f / denom[hw];
#pragma unroll
    for (int j = 0; j < 4; ++j) {
      int e = e0 + te*4 + j;
      size_t idx = (size_t)n*EE + e;
      float v = w1*Xbn[idx] + w4*num[idx]*rd;
      if (Abu) v += w2*(abu[i][j] + Lbu[(size_t)hw*EE + e]);
      if (Atd) v += w3*(atd[i][j] + Ltd[(size_t)hw*EE + e]);
      O[idx] = v;
    }
  }
}

// ---------------- final transpose: ws slots [l][n][e] -> out [b][e][hw][5] --
__global__ __launch_bounds__(256) void k_transpose(const float* __restrict__ ws,
                                                   float* __restrict__ out) {
  __shared__ float tile[5][32][33];
  int t = threadIdx.x;
  int hw0 = blockIdx.x * 32, e0 = blockIdx.y * 32, b = blockIdx.z;
  int tr = t >> 5, tc = t & 31;
#pragma unroll
  for (int l = 0; l < 5; ++l) {
    const float* src = ws + (size_t)l*NEs + ((size_t)(b*PP + hw0))*EE + e0;
    for (int p = 0; p < 4; ++p)
      tile[l][tr + 8*p][tc] = src[(size_t)(tr + 8*p)*EE + tc];
  }
  __syncthreads();
  for (int p = 0; p < 4; ++p) {
    int e = tr + 8*p;
    float* dst = out + (((size_t)(b*EE + e0 + e))*PP + (size_t)(hw0 + tc))*5;
#pragma unroll
    for (int l = 0; l < 5; ++l) dst[l] = tile[l][tc][e];
  }
}

// ---------------------------------------------------------------------------
extern "C" void kernel_launch(void* const* d_in, const int* in_sizes, int n_in,
                              void* d_out, int out_size, void* d_ws, size_t ws_size,
                              hipStream_t stream) {
  const float* x     = (const float*)d_in[0];
  const float* convw = (const float*)d_in[1];
  const float* convb = (const float*)d_in[2];
  const float* bu_w  = (const float*)d_in[3];
  const float* bu_b  = (const float*)d_in[4];
  const float* td_w  = (const float*)d_in[5];
  const float* td_b  = (const float*)d_in[6];
  const float* bn_g  = (const float*)d_in[7];
  const float* bn_b  = (const float*)d_in[8];
  const float* w1 = (const float*)d_in[9];
  const float* w2 = (const float*)d_in[10];
  const float* w3 = (const float*)d_in[11];
  const float* w4 = (const float*)d_in[12];
  float* out = (float*)d_out;
  float* ws  = (float*)d_ws;

  // ws layout (floats):
  float* slots = ws;                       // 5*NE  (cycle-0 prev, cycle-1 new)
  float* num   = ws + 5*NEs;               // NE
  float* locbu = ws + 6*NEs;               // 5*PE
  float* loctd = locbu + 5*PEs;            // 5*PE
  float* locb  = loctd + 5*PEs;            // 40960
  float* stats = locb + 40960;             // 1024
  float* ssbuf = stats + 1024;             // 1024
  float* srow  = ssbuf + 1024;             // 8192
  float* denom = srow + 8192;              // 1024
  unsigned short* Xbf  = (unsigned short*)(denom + 1024);  // NE bf16 (8MB)
  unsigned short* XbfT = Xbf + NEs;                        // NE bf16 (8MB)
  // total ~139 MB

  k_locb<<<4, 256, 0, stream>>>(locb);
  k_loclin<<<dim3(1024, 10), 256, 0, stream>>>(locb, bu_w, bu_b, td_w, td_b, locbu, loctd);
  k_conv<<<1024, 256, 0, stream>>>(x, convw, convb, slots);
  hipMemsetAsync(slots + NEs, 0, 4*NEs*sizeof(float), stream);   // levels 1..4 = 0

  for (int cyc = 0; cyc < 2; ++cyc) {
    for (int l = 0; l < 5; ++l) {
      float* X = (cyc == 0) ? (slots + (size_t)l*NEs) : (out + (size_t)l*NEs);
      hipMemsetAsync(stats, 0, 1024*sizeof(float), stream);
      k_bnstats<<<256, 512, 0, stream>>>(X, stats);
      k_bnfin<<<1, 512, 0, stream>>>(stats, bn_g + (size_t)l*EE, bn_b + (size_t)l*EE, ssbuf);
      k_bnapply<<<4096, 256, 0, stream>>>(X, ssbuf);
      k_tobf<<<dim3(32, 16, 8), 256, 0, stream>>>(X, Xbf, XbfT);
      k_attn_mfma<<<512, 64, 0, stream>>>(Xbf, XbfT, num, srow);
      k_denom<<<4, 256, 0, stream>>>(srow, denom);
      const float* Abu = nullptr;
      const float* Atd = nullptr;
      if (l > 0) Abu = (cyc == 0) ? (slots + (size_t)(l-1)*NEs) : (out + (size_t)(l-1)*NEs);
      if (l < 4) Atd = (cyc == 0) ? (slots + (size_t)(l+1)*NEs) : (out + (size_t)(l+1)*NEs);
      float* O = (cyc == 0) ? (out + (size_t)l*NEs) : (slots + (size_t)l*NEs);
      k_update<<<dim3(128, 8), 256, 0, stream>>>(X, num, denom,
          Abu, bu_w + (size_t)l*EE*FANC, locbu + (size_t)l*PEs,
          Atd, td_w + (size_t)l*EE*FANC, loctd + (size_t)l*PEs,
          w1, w2, w3, w4, O);
    }
  }
  k_transpose<<<dim3(32, 16, 8), 256, 0, stream>>>(slots, out);
}

// Round 3
// 1080.640 us; speedup vs baseline: 10.3659x; 5.0013x over previous
//
#include <hip/hip_runtime.h>

// ---------------------------------------------------------------------------
// GLOM forward. Round 3: everything matmul-shaped on bf16 MFMA tiled GEMMs.
// B=8, H=W=32, P=1024, N=8192 tokens, E=512, LF=10, FAN=552.
// ---------------------------------------------------------------------------

#define PI_F 3.14159265358979323846f

static constexpr int   PP    = 1024;
static constexpr int   NT    = 8192;
static constexpr int   EE    = 512;
static constexpr int   FANC  = 552;
static constexpr float BETA_F = 0.001f;
static constexpr float EPS_F  = 1e-5f;
static constexpr size_t NEs = (size_t)NT * EE;   // 4,194,304
static constexpr size_t PEs = (size_t)PP * EE;   //   524,288
static constexpr size_t SEs = (size_t)NT * PP;   // 8,388,608  (P matrix)

typedef __attribute__((ext_vector_type(8))) short short8v;  // 8 bf16
typedef __attribute__((ext_vector_type(4))) float f32x4;
typedef unsigned short u16;

__device__ __forceinline__ u16 f2bf(float x) {
  unsigned u = __float_as_uint(x);
  return (u16)((u + (((u >> 16) & 1u) + 0x7fffu)) >> 16);   // RNE
}
__device__ __forceinline__ float bf2f(u16 h) {
  return __uint_as_float(((unsigned)h) << 16);
}

// async global->LDS, 16B per lane; lds base must be wave-uniform
__device__ __forceinline__ void gll16(const u16* g, u16* l) {
  __builtin_amdgcn_global_load_lds(
      (const __attribute__((address_space(1))) unsigned int*)g,
      (__attribute__((address_space(3))) unsigned int*)l, 16, 0, 0);
}

// swizzled LDS read: tile row-major [rows][64] bf16 (128B rows), chunk cb in 0..7
__device__ __forceinline__ short8v ldsrd(const char* base, int row, int cb) {
  return *(const short8v*)(base + row*128 + (((cb ^ (row & 7)) << 4)));
}

// ---- shared GEMM segment: C(64xBNcols=128) += A(64xK) * B(128xK)^T --------
// As 8KB, Bs 16KB, XOR-swizzled via pre-swizzled global source chunks.
__device__ __forceinline__ void gemm_seg(
    const u16* __restrict__ Ab, int aStr,
    const u16* __restrict__ Bb, int bStr,
    int nsteps, char* As, char* Bs, int wbu, int lane, f32x4 (&acc)[2][4]) {
  int w = wbu >> 6, wr = w & 1, wc = w >> 1, lo = lane & 15, g = lane >> 4;
  for (int st = 0; st < nsteps; ++st) {
    int kk = st * 64;
    __syncthreads();
#pragma unroll
    for (int j = 0; j < 2; ++j) {        // A: 512 chunks of 16B
      int i = j*256 + wbu + lane;
      int r = i >> 3, c = (i & 7) ^ (r & 7);
      gll16(Ab + (size_t)r*aStr + kk + c*8, (u16*)(As + (j*256 + wbu)*16));
    }
#pragma unroll
    for (int j = 0; j < 4; ++j) {        // B: 1024 chunks of 16B
      int i = j*256 + wbu + lane;
      int r = i >> 3, c = (i & 7) ^ (r & 7);
      gll16(Bb + (size_t)r*bStr + kk + c*8, (u16*)(Bs + (j*256 + wbu)*16));
    }
    __syncthreads();                     // drains vmcnt before reads
#pragma unroll
    for (int h = 0; h < 2; ++h) {
      int cb = h*4 + g;
      short8v a0 = ldsrd(As, wr*32 + lo,      cb);
      short8v a1 = ldsrd(As, wr*32 + 16 + lo, cb);
#pragma unroll
      for (int j = 0; j < 4; ++j) {
        short8v bb = ldsrd(Bs, wc*64 + j*16 + lo, cb);
        acc[0][j] = __builtin_amdgcn_mfma_f32_16x16x32_bf16(a0, bb, acc[0][j], 0, 0, 0);
        acc[1][j] = __builtin_amdgcn_mfma_f32_16x16x32_bf16(a1, bb, acc[1][j], 0, 0, 0);
      }
    }
  }
}

// ---------------- positional-encoding table [P,40] --------------------------
__global__ void k_locb(float* __restrict__ locb) {
  int q = blockIdx.x * blockDim.x + threadIdx.x;
  if (q >= PP) return;
  int h = q >> 5, w = q & 31;
  float ph = 2.f * (float)h / 32.f - 1.f;
  float pw = 2.f * (float)w / 32.f - 1.f;
  float* d = locb + (size_t)q * 40;
#pragma unroll
  for (int j = 0; j < 10; ++j) {
    float f = (float)(1 << j) * PI_F;
    float ah = f * ph, aw = f * pw;
    d[2*j]     = sinf(ah); d[2*j+1]  = cosf(ah);
    d[20+2*j]  = sinf(aw); d[21+2*j] = cosf(aw);
  }
}

// ---- Lcomb[l][q][e] = w2*(loc@Wbu_loc + bu_b)·[l>0] + w3*(...td...)·[l<4] --
__global__ __launch_bounds__(256) void k_loccomb(const float* __restrict__ locb,
    const float* __restrict__ buw, const float* __restrict__ bub,
    const float* __restrict__ tdw, const float* __restrict__ tdb,
    const float* w2p, const float* w3p, u16* __restrict__ Lc) {
  int q = blockIdx.x, l = blockIdx.y, t = threadIdx.x;
  __shared__ float lb[40];
  if (t < 40) lb[t] = locb[(size_t)q*40 + t];
  __syncthreads();
  float w2 = *w2p, w3 = *w3p;
  for (int e = t; e < EE; e += 256) {
    float acc = 0.f;
    if (l > 0) {
      const float* wr = buw + ((size_t)l*EE + e)*FANC + EE;
      float a = bub[(size_t)l*EE + e];
#pragma unroll
      for (int f = 0; f < 40; ++f) a += lb[f]*wr[f];
      acc += w2 * a;
    }
    if (l < 4) {
      const float* wr = tdw + ((size_t)l*EE + e)*FANC + EE;
      float a = tdb[(size_t)l*EE + e];
#pragma unroll
      for (int f = 0; f < 40; ++f) a += lb[f]*wr[f];
      acc += w3 * a;
    }
    Lc[(size_t)l*PEs + (size_t)q*EE + e] = f2bf(acc);
  }
}

// ---- weights -> bf16 with w2/w3 folded: W*_s[l][e][0..511] ----------------
__global__ __launch_bounds__(256) void k_wconv(const float* __restrict__ buw,
    const float* __restrict__ tdw, const float* w2p, const float* w3p,
    u16* __restrict__ Wbu, u16* __restrict__ Wtd) {
  int gid = blockIdx.x*256 + threadIdx.x;   // 0..163839
  int which = blockIdx.y;
  int k8 = gid & 63;
  int row = gid >> 6;                        // l*512+e
  const float* src = (which ? tdw : buw) + (size_t)row*FANC + k8*8;
  float s = which ? *w3p : *w2p;
  u16* dst = (which ? Wtd : Wbu) + (size_t)row*EE + k8*8;
  short8v o;
#pragma unroll
  for (int j = 0; j < 8; ++j) o[j] = (short)f2bf(s*src[j]);
  *(short8v*)dst = o;
}

// ---------------- patch conv as GEMM: z[n,e] f32 ----------------------------
__global__ __launch_bounds__(256) void k_conv(const float* __restrict__ x,
    const float* __restrict__ cw, const float* __restrict__ cb,
    float* __restrict__ z) {
  __shared__ float patch[8][192];
  int t = threadIdx.x;
  int n0 = blockIdx.x * 8;
  for (int i = t; i < 8*192; i += 256) {
    int tok = i / 192, f = i - tok*192;
    int n = n0 + tok;
    int b = n >> 10, hw = n & 1023, h = hw >> 5, w = hw & 31;
    int c = f >> 6, r = f & 63, kh = r >> 3, kw = r & 7;
    patch[tok][f] = x[((size_t)(b*3 + c)*256 + (size_t)(h*8 + kh))*256 + (w*8 + kw)];
  }
  __syncthreads();
  for (int u = 0; u < 2; ++u) {
    int e = t + 256*u;
    float acc[8];
    float bias = cb[e];
#pragma unroll
    for (int tok = 0; tok < 8; ++tok) acc[tok] = bias;
    const float4* wr = (const float4*)(cw + (size_t)e*192);
    for (int f4 = 0; f4 < 48; ++f4) {
      float4 wv = wr[f4];
#pragma unroll
      for (int tok = 0; tok < 8; ++tok) {
        float4 pv = ((const float4*)patch[tok])[f4];
        acc[tok] += wv.x*pv.x + wv.y*pv.y + wv.z*pv.z + wv.w*pv.w;
      }
    }
    for (int tok = 0; tok < 8; ++tok) z[(size_t)(n0+tok)*EE + e] = acc[tok];
  }
}

// ---- initial f32 state -> Bpre bf16 ---------------------------------------
__global__ __launch_bounds__(256) void k_pre2bf(const float* __restrict__ X,
                                                u16* __restrict__ B) {
  size_t i = ((size_t)blockIdx.x*256 + threadIdx.x)*8;
  float4 v0 = *(const float4*)(X + i), v1 = *(const float4*)(X + i + 4);
  short8v o;
  o[0]=(short)f2bf(v0.x); o[1]=(short)f2bf(v0.y); o[2]=(short)f2bf(v0.z); o[3]=(short)f2bf(v0.w);
  o[4]=(short)f2bf(v1.x); o[5]=(short)f2bf(v1.y); o[6]=(short)f2bf(v1.z); o[7]=(short)f2bf(v1.w);
  *(short8v*)(B + i) = o;
}

// ---------------- BatchNorm stats ------------------------------------------
template<int F32>
__global__ __launch_bounds__(512) void k_bnstats(const float* __restrict__ Xf,
    const u16* __restrict__ Xh, float* __restrict__ stats) {
  int t = threadIdx.x;
  int r0 = blockIdx.x * 32;
  float s = 0.f, sq = 0.f;
  for (int r = 0; r < 32; ++r) {
    float v = F32 ? Xf[(size_t)(r0+r)*EE + t] : bf2f(Xh[(size_t)(r0+r)*EE + t]);
    s += v; sq += v*v;
  }
  atomicAdd(&stats[t], s);
  atomicAdd(&stats[EE+t], sq);
}

__global__ void k_bnfin(const float* __restrict__ stats, const float* __restrict__ g,
                        const float* __restrict__ bta, float* __restrict__ ss) {
  int t = threadIdx.x;
  float mean = stats[t] * (1.f/8192.f);
  float var  = stats[EE+t] * (1.f/8192.f) - mean*mean;
  var = fmaxf(var, 0.f);
  float sc = g[t] * rsqrtf(var + EPS_F);
  ss[t]    = sc;
  ss[EE+t] = bta[t] - mean*sc;
}

// ---- BN apply + bf16 + transposed bf16 (fused) -----------------------------
template<int INF32>
__global__ __launch_bounds__(256) void k_bnx(const float* __restrict__ Xf,
    const u16* __restrict__ Xh, float* __restrict__ XfOut,
    u16* __restrict__ Bpost, u16* __restrict__ XbfT, const float* __restrict__ ss) {
  __shared__ u16 tile[32][34];
  int b = blockIdx.z;
  int p0 = blockIdx.x * 32, e0 = blockIdx.y * 32;
  int tr = threadIdx.x >> 5, tc = threadIdx.x & 31;
  int c = e0 + tc;
  float sc = ss[c], sh = ss[EE + c];
#pragma unroll
  for (int i = 0; i < 4; ++i) {
    int p = tr + 8*i;
    size_t idx = (size_t)(b*PP + p0 + p)*EE + c;
    float v = INF32 ? Xf[idx] : bf2f(Xh[idx]);
    float y = v*sc + sh;
    if (INF32) XfOut[idx] = y;
    u16 us = f2bf(y);
    Bpost[idx] = us;
    tile[p][tc] = us;
  }
  __syncthreads();
#pragma unroll
  for (int i = 0; i < 4; ++i) {
    int e = tr + 8*i;
    XbfT[(size_t)(b*EE + e0 + e)*PP + p0 + tc] = tile[tc][e];
  }
}

// ---- GEMM1: P = exp(beta * X X^T) per batch, + denom atomics ---------------
__global__ __launch_bounds__(256) void k_gemm1(const u16* __restrict__ Xb,
    u16* __restrict__ P, float* __restrict__ denom) {
  __shared__ char As[8192];
  __shared__ char Bs[16384];
  int tid = threadIdx.x, lane = tid & 63;
  int wbu = __builtin_amdgcn_readfirstlane(tid & ~63);
  int q0 = blockIdx.x*64, k0 = blockIdx.y*128, b = blockIdx.z;
  int w = wbu >> 6, wr = w & 1, wc = w >> 1, lo = lane & 15, g = lane >> 4;
  const u16* Abase = Xb + ((size_t)(b*PP + q0))*EE;
  const u16* Bbase = Xb + ((size_t)(b*PP + k0))*EE;
  f32x4 acc[2][4] = {};
  gemm_seg(Abase, EE, Bbase, EE, 8, As, Bs, wbu, lane, acc);
  float rs[2][4] = {};
#pragma unroll
  for (int i = 0; i < 2; ++i)
#pragma unroll
    for (int j = 0; j < 4; ++j)
#pragma unroll
      for (int r = 0; r < 4; ++r) {
        float ex = __expf(BETA_F * acc[i][j][r]);
        rs[i][r] += ex;
        int q = q0 + wr*32 + i*16 + g*4 + r;
        int k = k0 + wc*64 + j*16 + lo;
        P[((size_t)(b*PP) + q)*PP + k] = f2bf(ex);
      }
#pragma unroll
  for (int i = 0; i < 2; ++i)
#pragma unroll
    for (int r = 0; r < 4; ++r) {
      float v = rs[i][r];
      v += __shfl_xor(v, 1); v += __shfl_xor(v, 2);
      v += __shfl_xor(v, 4); v += __shfl_xor(v, 8);
      if (lo == 0) atomicAdd(&denom[q0 + wr*32 + i*16 + g*4 + r], v);
    }
}

// ---- P *= w4/denom[q] in place --------------------------------------------
__global__ __launch_bounds__(256) void k_pscale(u16* __restrict__ P,
    const float* __restrict__ denom, const float* __restrict__ w4p) {
  size_t i8 = ((size_t)blockIdx.x*256 + threadIdx.x)*8;
  int q = (int)((i8 >> 10) & 1023);
  float s = w4p[0] / denom[q];
  short8v v = *(short8v*)(P + i8);
#pragma unroll
  for (int j = 0; j < 8; ++j) v[j] = (short)f2bf(bf2f((u16)v[j]) * s);
  *(short8v*)(P + i8) = v;
}

// ---- mega GEMM: O = bu + td + PV + w1*Xbn + Lcomb, out bf16 ---------------
template<int XBNF32>
__global__ __launch_bounds__(256) void k_mega(
    const u16* aBu, const u16* bBu, int stBu,
    const u16* aTd, const u16* bTd, int stTd,
    const u16* __restrict__ Pm, const u16* __restrict__ Vt,
    const float* __restrict__ Xf, const u16* __restrict__ Xh,
    const u16* __restrict__ Lc, const float* __restrict__ w1p,
    u16* __restrict__ Obf) {
  __shared__ char As[8192];
  __shared__ char Bs[16384];
  int tid = threadIdx.x, lane = tid & 63;
  int wbu = __builtin_amdgcn_readfirstlane(tid & ~63);
  int w = wbu >> 6, wr = w & 1, wc = w >> 1, lo = lane & 15, g = lane >> 4;
  int n0 = blockIdx.x*64, e0 = blockIdx.y*128;
  int b = n0 >> 10;
  f32x4 acc[2][4] = {};
  if (stBu) gemm_seg(aBu + (size_t)n0*EE, EE, bBu + (size_t)e0*EE, EE, 8, As, Bs, wbu, lane, acc);
  if (stTd) gemm_seg(aTd + (size_t)n0*EE, EE, bTd + (size_t)e0*EE, EE, 8, As, Bs, wbu, lane, acc);
  gemm_seg(Pm + (size_t)n0*PP, PP, Vt + (size_t)b*EE*PP + (size_t)e0*PP, PP, 16, As, Bs, wbu, lane, acc);
  float w1 = *w1p;
#pragma unroll
  for (int i = 0; i < 2; ++i)
#pragma unroll
    for (int j = 0; j < 4; ++j)
#pragma unroll
      for (int r = 0; r < 4; ++r) {
        int n = n0 + wr*32 + i*16 + g*4 + r;
        int e = e0 + wc*64 + j*16 + lo;
        size_t idx = (size_t)n*EE + e;
        float xb = XBNF32 ? Xf[idx] : bf2f(Xh[idx]);
        float v = acc[i][j][r] + w1*xb + bf2f(Lc[(size_t)(n & 1023)*EE + e]);
        Obf[idx] = f2bf(v);
      }
}

// ---- final transpose: Bpre bf16 [l][b][hw][e] -> out f32 [b][e][hw][5] -----
__global__ __launch_bounds__(256) void k_transpose_bf(const u16* __restrict__ Bpre,
                                                      float* __restrict__ out) {
  __shared__ u16 tile[5][32][34];
  int t = threadIdx.x;
  int hw0 = blockIdx.x * 32, e0 = blockIdx.y * 32, b = blockIdx.z;
  int tr = t >> 5, tc = t & 31;
#pragma unroll
  for (int l = 0; l < 5; ++l) {
    const u16* src = Bpre + (size_t)l*NEs + ((size_t)(b*PP + hw0))*EE + e0;
    for (int p = 0; p < 4; ++p)
      tile[l][tr + 8*p][tc] = src[(size_t)(tr + 8*p)*EE + tc];
  }
  __syncthreads();
  for (int p = 0; p < 4; ++p) {
    int e = tr + 8*p;
    float* dst = out + (((size_t)(b*EE + e0 + e))*PP + (size_t)(hw0 + tc))*5;
#pragma unroll
    for (int l = 0; l < 5; ++l) dst[l] = bf2f(tile[l][tc][e]);
  }
}

// ---------------------------------------------------------------------------
extern "C" void kernel_launch(void* const* d_in, const int* in_sizes, int n_in,
                              void* d_out, int out_size, void* d_ws, size_t ws_size,
                              hipStream_t stream) {
  const float* x     = (const float*)d_in[0];
  const float* convw = (const float*)d_in[1];
  const float* convb = (const float*)d_in[2];
  const float* bu_w  = (const float*)d_in[3];
  const float* bu_b  = (const float*)d_in[4];
  const float* td_w  = (const float*)d_in[5];
  const float* td_b  = (const float*)d_in[6];
  const float* bn_g  = (const float*)d_in[7];
  const float* bn_b  = (const float*)d_in[8];
  const float* w1 = (const float*)d_in[9];
  const float* w2 = (const float*)d_in[10];
  const float* w3 = (const float*)d_in[11];
  const float* w4 = (const float*)d_in[12];
  float* out = (float*)d_out;

  // ws layout (bf16 units unless noted)
  u16* Bpre  = (u16*)d_ws;                  // 5*NE   (state bf16; final emb staging)
  u16* Bpost = Bpre + 5*NEs;                // 2*NE   (rotating post-BN slots)
  u16* P     = Bpost + 2*NEs;               // NT*PP
  u16* XbfT  = P + SEs;                     // NE     ([b][e][p])
  u16* Lcomb = XbfT + NEs;                  // 5*PE
  u16* Wbu_s = Lcomb + 5*PEs;               // 5*512*512
  u16* Wtd_s = Wbu_s + (size_t)5*EE*EE;     // 5*512*512
  float* locb  = (float*)(Wtd_s + (size_t)5*EE*EE);  // 40960 f32
  float* stats = locb + 40960;              // 1024 f32
  float* ssbuf = stats + 1024;              // 1024 f32
  float* denom = ssbuf + 1024;              // 1024 f32
  // total ~94.5 MB

  // setup
  k_locb<<<4, 256, 0, stream>>>(locb);
  k_loccomb<<<dim3(1024, 5), 256, 0, stream>>>(locb, bu_w, bu_b, td_w, td_b, w2, w3, Lcomb);
  k_wconv<<<dim3(640, 2), 256, 0, stream>>>(bu_w, td_w, w2, w3, Wbu_s, Wtd_s);
  k_conv<<<1024, 256, 0, stream>>>(x, convw, convb, out);        // d_out slot 0 = f32 state
  hipMemsetAsync(out + NEs, 0, 4*NEs*sizeof(float), stream);     // levels 1..4 zero
  k_pre2bf<<<10240, 256, 0, stream>>>(out, Bpre);                // initial bf16 state

  for (int cyc = 0; cyc < 2; ++cyc) {
    for (int l = 0; l < 5; ++l) {
      u16* BpostL = Bpost + (size_t)(l & 1)*NEs;
      hipMemsetAsync(stats, 0, 4096, stream);
      if (cyc == 0) k_bnstats<1><<<256, 512, 0, stream>>>(out + (size_t)l*NEs, nullptr, stats);
      else          k_bnstats<0><<<256, 512, 0, stream>>>(nullptr, Bpre + (size_t)l*NEs, stats);
      k_bnfin<<<1, 512, 0, stream>>>(stats, bn_g + (size_t)l*EE, bn_b + (size_t)l*EE, ssbuf);
      if (cyc == 0)
        k_bnx<1><<<dim3(32,16,8), 256, 0, stream>>>(out + (size_t)l*NEs, nullptr,
            out + (size_t)l*NEs, BpostL, XbfT, ssbuf);
      else
        k_bnx<0><<<dim3(32,16,8), 256, 0, stream>>>(nullptr, Bpre + (size_t)l*NEs,
            nullptr, BpostL, XbfT, ssbuf);
      hipMemsetAsync(denom, 0, 4096, stream);
      k_gemm1<<<dim3(16,8,8), 256, 0, stream>>>(BpostL, P, denom);
      k_pscale<<<4096, 256, 0, stream>>>(P, denom, w4);
      const u16* aBu = (l > 0) ? Bpost + (size_t)((l-1) & 1)*NEs : nullptr;
      const u16* bBu = (l > 0) ? Wbu_s + (size_t)l*EE*EE : nullptr;
      const u16* aTd = (l < 4) ? Bpre + (size_t)(l+1)*NEs : nullptr;
      const u16* bTd = (l < 4) ? Wtd_s + (size_t)l*EE*EE : nullptr;
      if (cyc == 0)
        k_mega<1><<<dim3(128,4), 256, 0, stream>>>(aBu, bBu, (l>0)?8:0,
            aTd, bTd, (l<4)?8:0, P, XbfT,
            out + (size_t)l*NEs, nullptr, Lcomb + (size_t)l*PEs, w1,
            Bpre + (size_t)l*NEs);
      else
        k_mega<0><<<dim3(128,4), 256, 0, stream>>>(aBu, bBu, (l>0)?8:0,
            aTd, bTd, (l<4)?8:0, P, XbfT,
            nullptr, BpostL, Lcomb + (size_t)l*PEs, w1,
            Bpre + (size_t)l*NEs);
    }
  }
  k_transpose_bf<<<dim3(32,16,8), 256, 0, stream>>>(Bpre, out);
}

// Round 4
// 797.289 us; speedup vs baseline: 14.0499x; 1.3554x over previous
//
#include <hip/hip_runtime.h>

// ---------------------------------------------------------------------------
// GLOM forward. Round 4: coalesced loc-precompute, producer-fused BN stats,
// pscale folded into mega (PV-first + register scale), all-bf16 state.
// B=8, H=W=32, P=1024, N=8192 tokens, E=512, LF=10, FAN=552.
// ---------------------------------------------------------------------------

#define PI_F 3.14159265358979323846f

static constexpr int   PP    = 1024;
static constexpr int   NT    = 8192;
static constexpr int   EE    = 512;
static constexpr int   FANC  = 552;
static constexpr float BETA_F = 0.001f;
static constexpr float EPS_F  = 1e-5f;
static constexpr size_t NEs = (size_t)NT * EE;   // 4,194,304
static constexpr size_t PEs = (size_t)PP * EE;   //   524,288
static constexpr size_t SEs = (size_t)NT * PP;   // 8,388,608

typedef __attribute__((ext_vector_type(8))) short short8v;  // 8 bf16
typedef __attribute__((ext_vector_type(4))) float f32x4;
typedef unsigned short u16;

__device__ __forceinline__ u16 f2bf(float x) {
  unsigned u = __float_as_uint(x);
  return (u16)((u + (((u >> 16) & 1u) + 0x7fffu)) >> 16);   // RNE
}
__device__ __forceinline__ float bf2f(u16 h) {
  return __uint_as_float(((unsigned)h) << 16);
}

// async global->LDS, 16B per lane; lds base must be wave-uniform
__device__ __forceinline__ void gll16(const u16* g, u16* l) {
  __builtin_amdgcn_global_load_lds(
      (const __attribute__((address_space(1))) unsigned int*)g,
      (__attribute__((address_space(3))) unsigned int*)l, 16, 0, 0);
}

// swizzled LDS read: tile row-major [rows][64] bf16 (128B rows), chunk cb 0..7
__device__ __forceinline__ short8v ldsrd(const char* base, int row, int cb) {
  return *(const short8v*)(base + row*128 + (((cb ^ (row & 7)) << 4)));
}

// ---- shared GEMM segment: C(64x128) += A(64xK) * B(128xK)^T ---------------
__device__ __forceinline__ void gemm_seg(
    const u16* __restrict__ Ab, int aStr,
    const u16* __restrict__ Bb, int bStr,
    int nsteps, char* As, char* Bs, int wbu, int lane, f32x4 (&acc)[2][4]) {
  int w = wbu >> 6, wr = w & 1, wc = w >> 1, lo = lane & 15, g = lane >> 4;
  for (int st = 0; st < nsteps; ++st) {
    int kk = st * 64;
    __syncthreads();
#pragma unroll
    for (int j = 0; j < 2; ++j) {        // A: 512 chunks of 16B
      int i = j*256 + wbu + lane;
      int r = i >> 3, c = (i & 7) ^ (r & 7);
      gll16(Ab + (size_t)r*aStr + kk + c*8, (u16*)(As + (j*256 + wbu)*16));
    }
#pragma unroll
    for (int j = 0; j < 4; ++j) {        // B: 1024 chunks of 16B
      int i = j*256 + wbu + lane;
      int r = i >> 3, c = (i & 7) ^ (r & 7);
      gll16(Bb + (size_t)r*bStr + kk + c*8, (u16*)(Bs + (j*256 + wbu)*16));
    }
    __syncthreads();                     // drains vmcnt before reads
#pragma unroll
    for (int h = 0; h < 2; ++h) {
      int cb = h*4 + g;
      short8v a0 = ldsrd(As, wr*32 + lo,      cb);
      short8v a1 = ldsrd(As, wr*32 + 16 + lo, cb);
#pragma unroll
      for (int j = 0; j < 4; ++j) {
        short8v bb = ldsrd(Bs, wc*64 + j*16 + lo, cb);
        acc[0][j] = __builtin_amdgcn_mfma_f32_16x16x32_bf16(a0, bb, acc[0][j], 0, 0, 0);
        acc[1][j] = __builtin_amdgcn_mfma_f32_16x16x32_bf16(a1, bb, acc[1][j], 0, 0, 0);
      }
    }
  }
}

// ---------------- positional-encoding table [P,40] --------------------------
__global__ void k_locb(float* __restrict__ locb) {
  int q = blockIdx.x * blockDim.x + threadIdx.x;
  if (q >= PP) return;
  int h = q >> 5, w = q & 31;
  float ph = 2.f * (float)h / 32.f - 1.f;
  float pw = 2.f * (float)w / 32.f - 1.f;
  float* d = locb + (size_t)q * 40;
#pragma unroll
  for (int j = 0; j < 10; ++j) {
    float f = (float)(1 << j) * PI_F;
    float ah = f * ph, aw = f * pw;
    d[2*j]     = sinf(ah); d[2*j+1]  = cosf(ah);
    d[20+2*j]  = sinf(aw); d[21+2*j] = cosf(aw);
  }
}

// ---- Wcomb[l][f][e] = w2*buw[l][e][512+f]*(l>0) + w3*tdw[...]*(l<4) --------
// bcomb[l][e] similarly from biases. One pass over the scattered layout.
__global__ __launch_bounds__(256) void k_wcombT(
    const float* __restrict__ buw, const float* __restrict__ bub,
    const float* __restrict__ tdw, const float* __restrict__ tdb,
    const float* w2p, const float* w3p,
    float* __restrict__ Wcomb, float* __restrict__ bcomb) {
  int l = blockIdx.x, et = blockIdx.y, t = threadIdx.x;
  int e = et*64 + (t >> 2), fg = (t & 3)*10;
  float w2 = *w2p, w3 = *w3p;
  const float* bu = buw + ((size_t)l*EE + e)*FANC + EE;
  const float* td = tdw + ((size_t)l*EE + e)*FANC + EE;
#pragma unroll
  for (int j = 0; j < 10; ++j) {
    int f = fg + j;
    float v = 0.f;
    if (l > 0) v += w2 * bu[f];
    if (l < 4) v += w3 * td[f];
    Wcomb[((size_t)l*40 + f)*EE + e] = v;
  }
  if (fg == 0) {
    float bv = 0.f;
    if (l > 0) bv += w2 * bub[(size_t)l*EE + e];
    if (l < 4) bv += w3 * tdb[(size_t)l*EE + e];
    bcomb[(size_t)l*EE + e] = bv;
  }
}

// ---- Lcomb[l][q][e] via coalesced Wcomb, 16-q register blocking ------------
__global__ __launch_bounds__(256) void k_loccomb2(const float* __restrict__ locb,
    const float* __restrict__ Wcomb, const float* __restrict__ bcomb,
    u16* __restrict__ Lc) {
  int l = blockIdx.x, q0 = blockIdx.y * 16, t = threadIdx.x;
  __shared__ float lb[16][40];
  for (int i = t; i < 640; i += 256) lb[i/40][i%40] = locb[(size_t)(q0 + i/40)*40 + i%40];
  __syncthreads();
  float acc0[16] = {}, acc1[16] = {};
  const float* W = Wcomb + (size_t)l*40*EE;
#pragma unroll 8
  for (int f = 0; f < 40; ++f) {
    float wa = W[(size_t)f*EE + t];
    float wb = W[(size_t)f*EE + t + 256];
#pragma unroll
    for (int q = 0; q < 16; ++q) {
      acc0[q] += lb[q][f]*wa;
      acc1[q] += lb[q][f]*wb;
    }
  }
  float b0 = bcomb[(size_t)l*EE + t], b1 = bcomb[(size_t)l*EE + t + 256];
  u16* dst = Lc + (size_t)l*PEs + (size_t)q0*EE;
#pragma unroll
  for (int q = 0; q < 16; ++q) {
    dst[(size_t)q*EE + t]       = f2bf(acc0[q] + b0);
    dst[(size_t)q*EE + t + 256] = f2bf(acc1[q] + b1);
  }
}

// ---- weights -> bf16 with w2/w3 folded: W*_s[l][e][0..511] ----------------
__global__ __launch_bounds__(256) void k_wconv(const float* __restrict__ buw,
    const float* __restrict__ tdw, const float* w2p, const float* w3p,
    u16* __restrict__ Wbu, u16* __restrict__ Wtd) {
  int gid = blockIdx.x*256 + threadIdx.x;
  int which = blockIdx.y;
  int k8 = gid & 63;
  int row = gid >> 6;
  const float* src = (which ? tdw : buw) + (size_t)row*FANC + k8*8;
  float s = which ? *w3p : *w2p;
  u16* dst = (which ? Wtd : Wbu) + (size_t)row*EE + k8*8;
  short8v o;
#pragma unroll
  for (int j = 0; j < 8; ++j) o[j] = (short)f2bf(s*src[j]);
  *(short8v*)dst = o;
}

// ---------------- patch conv -> Bpre[0] bf16 + statsA[0] --------------------
__global__ __launch_bounds__(256) void k_conv(const float* __restrict__ x,
    const float* __restrict__ cw, const float* __restrict__ cb,
    u16* __restrict__ z, float* __restrict__ statsA) {
  __shared__ float patch[8][192];
  int t = threadIdx.x;
  int n0 = blockIdx.x * 8;
  for (int i = t; i < 8*192; i += 256) {
    int tok = i / 192, f = i - tok*192;
    int n = n0 + tok;
    int b = n >> 10, hw = n & 1023, h = hw >> 5, w = hw & 31;
    int c = f >> 6, r = f & 63, kh = r >> 3, kw = r & 7;
    patch[tok][f] = x[((size_t)(b*3 + c)*256 + (size_t)(h*8 + kh))*256 + (w*8 + kw)];
  }
  __syncthreads();
  for (int u = 0; u < 2; ++u) {
    int e = t + 256*u;
    float acc[8];
    float bias = cb[e];
#pragma unroll
    for (int tok = 0; tok < 8; ++tok) acc[tok] = bias;
    const float4* wr = (const float4*)(cw + (size_t)e*192);
    for (int f4 = 0; f4 < 48; ++f4) {
      float4 wv = wr[f4];
#pragma unroll
      for (int tok = 0; tok < 8; ++tok) {
        float4 pv = ((const float4*)patch[tok])[f4];
        acc[tok] += wv.x*pv.x + wv.y*pv.y + wv.z*pv.z + wv.w*pv.w;
      }
    }
    float s = 0.f, sq = 0.f;
#pragma unroll
    for (int tok = 0; tok < 8; ++tok) {
      z[(size_t)(n0+tok)*EE + e] = f2bf(acc[tok]);
      s += acc[tok]; sq += acc[tok]*acc[tok];
    }
    atomicAdd(&statsA[e], s);
    atomicAdd(&statsA[EE + e], sq);
  }
}

// ---- BN apply (stats->scale/shift inline) + bf16 + transposed bf16 ---------
__global__ __launch_bounds__(256) void k_bnx(const u16* __restrict__ Xh,
    const float* __restrict__ stats, const float* __restrict__ gam,
    const float* __restrict__ bta, u16* __restrict__ Bpost,
    u16* __restrict__ XbfT) {
  __shared__ u16 tile[32][34];
  __shared__ float ssl[2][32];
  int b = blockIdx.z;
  int p0 = blockIdx.x * 32, e0 = blockIdx.y * 32;
  int tr = threadIdx.x >> 5, tc = threadIdx.x & 31;
  if (threadIdx.x < 32) {
    int c = e0 + threadIdx.x;
    float mean = stats[c] * (1.f/8192.f);
    float var  = stats[EE + c] * (1.f/8192.f) - mean*mean;
    var = fmaxf(var, 0.f);
    float sc = gam[c] * rsqrtf(var + EPS_F);
    ssl[0][threadIdx.x] = sc;
    ssl[1][threadIdx.x] = bta[c] - mean*sc;
  }
  __syncthreads();
  float sc = ssl[0][tc], sh = ssl[1][tc];
#pragma unroll
  for (int i = 0; i < 4; ++i) {
    int p = tr + 8*i;
    size_t idx = (size_t)(b*PP + p0 + p)*EE + e0 + tc;
    u16 us = f2bf(bf2f(Xh[idx])*sc + sh);
    Bpost[idx] = us;
    tile[p][tc] = us;
  }
  __syncthreads();
#pragma unroll
  for (int i = 0; i < 4; ++i) {
    int e = tr + 8*i;
    XbfT[(size_t)(b*EE + e0 + e)*PP + p0 + tc] = tile[tc][e];
  }
}

// ---- GEMM1: P = exp(beta * X X^T) per batch, + denom atomics ---------------
__global__ __launch_bounds__(256) void k_gemm1(const u16* __restrict__ Xb,
    u16* __restrict__ P, float* __restrict__ denom) {
  __shared__ char As[8192];
  __shared__ char Bs[16384];
  int tid = threadIdx.x, lane = tid & 63;
  int wbu = __builtin_amdgcn_readfirstlane(tid & ~63);
  int q0 = blockIdx.x*64, k0 = blockIdx.y*128, b = blockIdx.z;
  int w = wbu >> 6, wr = w & 1, wc = w >> 1, lo = lane & 15, g = lane >> 4;
  const u16* Abase = Xb + ((size_t)(b*PP + q0))*EE;
  const u16* Bbase = Xb + ((size_t)(b*PP + k0))*EE;
  f32x4 acc[2][4] = {};
  gemm_seg(Abase, EE, Bbase, EE, 8, As, Bs, wbu, lane, acc);
  float rs[2][4] = {};
#pragma unroll
  for (int i = 0; i < 2; ++i)
#pragma unroll
    for (int j = 0; j < 4; ++j)
#pragma unroll
      for (int r = 0; r < 4; ++r) {
        float ex = __expf(BETA_F * acc[i][j][r]);
        rs[i][r] += ex;
        int q = q0 + wr*32 + i*16 + g*4 + r;
        int k = k0 + wc*64 + j*16 + lo;
        P[((size_t)(b*PP) + q)*PP + k] = f2bf(ex);
      }
#pragma unroll
  for (int i = 0; i < 2; ++i)
#pragma unroll
    for (int r = 0; r < 4; ++r) {
      float v = rs[i][r];
      v += __shfl_xor(v, 1); v += __shfl_xor(v, 2);
      v += __shfl_xor(v, 4); v += __shfl_xor(v, 8);
      if (lo == 0) atomicAdd(&denom[q0 + wr*32 + i*16 + g*4 + r], v);
    }
}

// ---- mega GEMM: O = PV*w4/denom + bu + td + w1*Xbn + Lcomb -----------------
// ACCST: accumulate next-cycle BN stats from outputs.
template<int ACCST>
__global__ __launch_bounds__(256) void k_mega(
    const u16* aBu, const u16* bBu, int stBu,
    const u16* aTd, const u16* bTd, int stTd,
    const u16* __restrict__ Pm, const u16* __restrict__ Vt,
    const u16* __restrict__ Xh, const u16* __restrict__ Lc,
    const float* __restrict__ w1p, const float* __restrict__ w4p,
    const float* __restrict__ denom, float* __restrict__ statsB,
    u16* __restrict__ Obf) {
  __shared__ char As[8192];
  __shared__ char Bs[16384];
  int tid = threadIdx.x, lane = tid & 63;
  int wbu = __builtin_amdgcn_readfirstlane(tid & ~63);
  int w = wbu >> 6, wr = w & 1, wc = w >> 1, lo = lane & 15, g = lane >> 4;
  int n0 = blockIdx.x*64, e0 = blockIdx.y*128;
  int b = n0 >> 10;
  f32x4 acc[2][4] = {};
  // PV first, then scale by w4/denom in registers
  gemm_seg(Pm + (size_t)n0*PP, PP, Vt + (size_t)b*EE*PP + (size_t)e0*PP, PP, 16,
           As, Bs, wbu, lane, acc);
  float w4 = *w4p;
#pragma unroll
  for (int i = 0; i < 2; ++i)
#pragma unroll
    for (int r = 0; r < 4; ++r) {
      int q = (n0 + wr*32 + i*16 + g*4 + r) & 1023;
      float s = w4 / denom[q];
#pragma unroll
      for (int j = 0; j < 4; ++j) acc[i][j][r] *= s;
    }
  if (stBu) gemm_seg(aBu + (size_t)n0*EE, EE, bBu + (size_t)e0*EE, EE, 8, As, Bs, wbu, lane, acc);
  if (stTd) gemm_seg(aTd + (size_t)n0*EE, EE, bTd + (size_t)e0*EE, EE, 8, As, Bs, wbu, lane, acc);
  float w1 = *w1p;
  float stS[4] = {}, stQ[4] = {};
#pragma unroll
  for (int i = 0; i < 2; ++i)
#pragma unroll
    for (int j = 0; j < 4; ++j)
#pragma unroll
      for (int r = 0; r < 4; ++r) {
        int n = n0 + wr*32 + i*16 + g*4 + r;
        int e = e0 + wc*64 + j*16 + lo;
        size_t idx = (size_t)n*EE + e;
        float v = acc[i][j][r] + w1*bf2f(Xh[idx]) + bf2f(Lc[(size_t)(n & 1023)*EE + e]);
        Obf[idx] = f2bf(v);
        if (ACCST) { stS[j] += v; stQ[j] += v*v; }
      }
  if (ACCST) {
#pragma unroll
    for (int j = 0; j < 4; ++j) {
      float s = stS[j], q2 = stQ[j];
      s  += __shfl_xor(s, 16);  s  += __shfl_xor(s, 32);
      q2 += __shfl_xor(q2, 16); q2 += __shfl_xor(q2, 32);
      if (g == 0) {
        int e = e0 + wc*64 + j*16 + lo;
        atomicAdd(&statsB[e], s);
        atomicAdd(&statsB[EE + e], q2);
      }
    }
  }
}

// ---- final transpose: Bpre bf16 [l][b][hw][e] -> out f32 [b][e][hw][5] -----
__global__ __launch_bounds__(256) void k_transpose_bf(const u16* __restrict__ Bpre,
                                                      float* __restrict__ out) {
  __shared__ u16 tile[5][32][34];
  int t = threadIdx.x;
  int hw0 = blockIdx.x * 32, e0 = blockIdx.y * 32, b = blockIdx.z;
  int tr = t >> 5, tc = t & 31;
#pragma unroll
  for (int l = 0; l < 5; ++l) {
    const u16* src = Bpre + (size_t)l*NEs + ((size_t)(b*PP + hw0))*EE + e0;
    for (int p = 0; p < 4; ++p)
      tile[l][tr + 8*p][tc] = src[(size_t)(tr + 8*p)*EE + tc];
  }
  __syncthreads();
  for (int p = 0; p < 4; ++p) {
    int e = tr + 8*p;
    float* dst = out + (((size_t)(b*EE + e0 + e))*PP + (size_t)(hw0 + tc))*5;
#pragma unroll
    for (int l = 0; l < 5; ++l) dst[l] = bf2f(tile[l][tc][e]);
  }
}

// ---------------------------------------------------------------------------
extern "C" void kernel_launch(void* const* d_in, const int* in_sizes, int n_in,
                              void* d_out, int out_size, void* d_ws, size_t ws_size,
                              hipStream_t stream) {
  const float* x     = (const float*)d_in[0];
  const float* convw = (const float*)d_in[1];
  const float* convb = (const float*)d_in[2];
  const float* bu_w  = (const float*)d_in[3];
  const float* bu_b  = (const float*)d_in[4];
  const float* td_w  = (const float*)d_in[5];
  const float* td_b  = (const float*)d_in[6];
  const float* bn_g  = (const float*)d_in[7];
  const float* bn_b  = (const float*)d_in[8];
  const float* w1 = (const float*)d_in[9];
  const float* w2 = (const float*)d_in[10];
  const float* w3 = (const float*)d_in[11];
  const float* w4 = (const float*)d_in[12];
  float* out = (float*)d_out;

  // ws layout
  u16* Bpre  = (u16*)d_ws;                      // 5*NE  (state; final emb)
  u16* Bpost = Bpre + 5*NEs;                    // 2*NE  (rotating post-BN)
  u16* P     = Bpost + 2*NEs;                   // NT*PP
  u16* XbfT  = P + SEs;                         // NE    ([b][e][p])
  u16* Lcomb = XbfT + NEs;                      // 5*PE
  u16* Wbu_s = Lcomb + 5*PEs;                   // 5*512*512
  u16* Wtd_s = Wbu_s + (size_t)5*EE*EE;         // 5*512*512
  float* locb   = (float*)(Wtd_s + (size_t)5*EE*EE);  // 40960
  float* Wcomb  = locb + 40960;                 // 5*40*512 = 102400
  float* bcomb  = Wcomb + 102400;               // 2560
  float* statsA = bcomb + 2560;                 // 5*1024 (initial-state stats)
  float* statsB = statsA + 5*1024;              // 5*1024 (cyc0-output stats)
  float* denomAll = statsB + 5*1024;            // 10*1024 (per cyc,l)
  // ~95 MB total

  // ---- setup ----
  k_locb<<<4, 256, 0, stream>>>(locb);
  k_wcombT<<<dim3(5, 8), 256, 0, stream>>>(bu_w, bu_b, td_w, td_b, w2, w3, Wcomb, bcomb);
  k_loccomb2<<<dim3(5, 64), 256, 0, stream>>>(locb, Wcomb, bcomb, Lcomb);
  k_wconv<<<dim3(640, 2), 256, 0, stream>>>(bu_w, td_w, w2, w3, Wbu_s, Wtd_s);
  hipMemsetAsync(Bpre + NEs, 0, 4*NEs*sizeof(u16), stream);       // levels 1..4 = 0
  hipMemsetAsync(statsA, 0, (5*1024 + 5*1024 + 10*1024)*sizeof(float), stream);
  k_conv<<<1024, 256, 0, stream>>>(x, convw, convb, Bpre, statsA);

  for (int cyc = 0; cyc < 2; ++cyc) {
    for (int l = 0; l < 5; ++l) {
      const float* statsSel = (cyc == 0 ? statsA : statsB) + (size_t)l*1024;
      u16* BpostL = Bpost + (size_t)(l & 1)*NEs;
      k_bnx<<<dim3(32,16,8), 256, 0, stream>>>(Bpre + (size_t)l*NEs, statsSel,
          bn_g + (size_t)l*EE, bn_b + (size_t)l*EE, BpostL, XbfT);
      float* dnm = denomAll + (size_t)(cyc*5 + l)*1024;
      k_gemm1<<<dim3(16,8,8), 256, 0, stream>>>(BpostL, P, dnm);
      const u16* aBu = (l > 0) ? Bpost + (size_t)((l-1) & 1)*NEs : nullptr;
      const u16* bBu = (l > 0) ? Wbu_s + (size_t)l*EE*EE : nullptr;
      const u16* aTd = (l < 4) ? Bpre + (size_t)(l+1)*NEs : nullptr;
      const u16* bTd = (l < 4) ? Wtd_s + (size_t)l*EE*EE : nullptr;
      if (cyc == 0)
        k_mega<1><<<dim3(128,4), 256, 0, stream>>>(aBu, bBu, (l>0)?8:0,
            aTd, bTd, (l<4)?8:0, P, XbfT, BpostL, Lcomb + (size_t)l*PEs,
            w1, w4, dnm, statsB + (size_t)l*1024, Bpre + (size_t)l*NEs);
      else
        k_mega<0><<<dim3(128,4), 256, 0, stream>>>(aBu, bBu, (l>0)?8:0,
            aTd, bTd, (l<4)?8:0, P, XbfT, BpostL, Lcomb + (size_t)l*PEs,
            w1, w4, dnm, nullptr, Bpre + (size_t)l*NEs);
    }
  }
  k_transpose_bf<<<dim3(32,16,8), 256, 0, stream>>>(Bpre, out);
}

// Round 5
// 788.170 us; speedup vs baseline: 14.2125x; 1.0116x over previous
//
#include <hip/hip_runtime.h>

// ---------------------------------------------------------------------------
// GLOM forward. Round 5: conv as im2col+MFMA GEMM; all GEMMs on 128x128
// m97-structure tiles (4 waves, 4x4 frags/wave, 32KB LDS, global_load_lds).
// B=8, H=W=32, P=1024, N=8192 tokens, E=512, LF=10, FAN=552.
// ---------------------------------------------------------------------------

#define PI_F 3.14159265358979323846f

static constexpr int   PP    = 1024;
static constexpr int   NT    = 8192;
static constexpr int   EE    = 512;
static constexpr int   FANC  = 552;
static constexpr int   KC    = 192;       // conv GEMM K (3*8*8)
static constexpr float BETA_F = 0.001f;
static constexpr float EPS_F  = 1e-5f;
static constexpr size_t NEs = (size_t)NT * EE;   // 4,194,304
static constexpr size_t PEs = (size_t)PP * EE;   //   524,288
static constexpr size_t SEs = (size_t)NT * PP;   // 8,388,608

typedef __attribute__((ext_vector_type(8))) short short8v;  // 8 bf16
typedef __attribute__((ext_vector_type(4))) float f32x4;
typedef unsigned short u16;

__device__ __forceinline__ u16 f2bf(float x) {
  unsigned u = __float_as_uint(x);
  return (u16)((u + (((u >> 16) & 1u) + 0x7fffu)) >> 16);   // RNE
}
__device__ __forceinline__ float bf2f(u16 h) {
  return __uint_as_float(((unsigned)h) << 16);
}

// async global->LDS, 16B per lane; lds base must be wave-uniform
__device__ __forceinline__ void gll16(const u16* g, u16* l) {
  __builtin_amdgcn_global_load_lds(
      (const __attribute__((address_space(1))) unsigned int*)g,
      (__attribute__((address_space(3))) unsigned int*)l, 16, 0, 0);
}

// swizzled LDS read: tile row-major [rows][64] bf16 (128B rows), chunk cb 0..7
__device__ __forceinline__ short8v ldsrd(const char* base, int row, int cb) {
  return *(const short8v*)(base + row*128 + (((cb ^ (row & 7)) << 4)));
}

// ---- 128x128 GEMM segment: C += A(128xK) * B(128xK)^T ---------------------
// As/Bs 16KB each. 4 waves in 2x2; per-wave 64x64 out (acc[4][4]).
__device__ __forceinline__ void gemm128(
    const u16* __restrict__ Ab, int aStr,
    const u16* __restrict__ Bb, int bStr,
    int nsteps, char* As, char* Bs, int wbu, int lane, f32x4 (&acc)[4][4]) {
  int w = wbu >> 6, wr = w & 1, wc = w >> 1, lo = lane & 15, g = lane >> 4;
  for (int st = 0; st < nsteps; ++st) {
    int kk = st * 64;
    __syncthreads();
#pragma unroll
    for (int j = 0; j < 4; ++j) {        // A: 1024 chunks of 16B
      int i = j*256 + wbu + lane;
      int r = i >> 3, c = (i & 7) ^ (r & 7);
      gll16(Ab + (size_t)r*aStr + kk + c*8, (u16*)(As + (j*256 + wbu)*16));
    }
#pragma unroll
    for (int j = 0; j < 4; ++j) {        // B: 1024 chunks of 16B
      int i = j*256 + wbu + lane;
      int r = i >> 3, c = (i & 7) ^ (r & 7);
      gll16(Bb + (size_t)r*bStr + kk + c*8, (u16*)(Bs + (j*256 + wbu)*16));
    }
    __syncthreads();                     // drains vmcnt before reads
#pragma unroll
    for (int h = 0; h < 2; ++h) {
      int cb = h*4 + g;
      short8v a[4], b[4];
#pragma unroll
      for (int m = 0; m < 4; ++m) a[m] = ldsrd(As, wr*64 + m*16 + lo, cb);
#pragma unroll
      for (int n = 0; n < 4; ++n) b[n] = ldsrd(Bs, wc*64 + n*16 + lo, cb);
#pragma unroll
      for (int m = 0; m < 4; ++m)
#pragma unroll
        for (int n = 0; n < 4; ++n)
          acc[m][n] = __builtin_amdgcn_mfma_f32_16x16x32_bf16(a[m], b[n], acc[m][n], 0, 0, 0);
    }
  }
}

// ---------------- positional-encoding table [P,40] --------------------------
__global__ void k_locb(float* __restrict__ locb) {
  int q = blockIdx.x * blockDim.x + threadIdx.x;
  if (q >= PP) return;
  int h = q >> 5, w = q & 31;
  float ph = 2.f * (float)h / 32.f - 1.f;
  float pw = 2.f * (float)w / 32.f - 1.f;
  float* d = locb + (size_t)q * 40;
#pragma unroll
  for (int j = 0; j < 10; ++j) {
    float f = (float)(1 << j) * PI_F;
    float ah = f * ph, aw = f * pw;
    d[2*j]     = sinf(ah); d[2*j+1]  = cosf(ah);
    d[20+2*j]  = sinf(aw); d[21+2*j] = cosf(aw);
  }
}

// ---- Wcomb[l][f][e], bcomb[l][e]: one pass over scattered weight layout ----
__global__ __launch_bounds__(256) void k_wcombT(
    const float* __restrict__ buw, const float* __restrict__ bub,
    const float* __restrict__ tdw, const float* __restrict__ tdb,
    const float* w2p, const float* w3p,
    float* __restrict__ Wcomb, float* __restrict__ bcomb) {
  int l = blockIdx.x, et = blockIdx.y, t = threadIdx.x;
  int e = et*64 + (t >> 2), fg = (t & 3)*10;
  float w2 = *w2p, w3 = *w3p;
  const float* bu = buw + ((size_t)l*EE + e)*FANC + EE;
  const float* td = tdw + ((size_t)l*EE + e)*FANC + EE;
#pragma unroll
  for (int j = 0; j < 10; ++j) {
    int f = fg + j;
    float v = 0.f;
    if (l > 0) v += w2 * bu[f];
    if (l < 4) v += w3 * td[f];
    Wcomb[((size_t)l*40 + f)*EE + e] = v;
  }
  if (fg == 0) {
    float bv = 0.f;
    if (l > 0) bv += w2 * bub[(size_t)l*EE + e];
    if (l < 4) bv += w3 * tdb[(size_t)l*EE + e];
    bcomb[(size_t)l*EE + e] = bv;
  }
}

// ---- Lcomb[l][q][e] via coalesced Wcomb, 16-q register blocking ------------
__global__ __launch_bounds__(256) void k_loccomb2(const float* __restrict__ locb,
    const float* __restrict__ Wcomb, const float* __restrict__ bcomb,
    u16* __restrict__ Lc) {
  int l = blockIdx.x, q0 = blockIdx.y * 16, t = threadIdx.x;
  __shared__ float lb[16][40];
  for (int i = t; i < 640; i += 256) lb[i/40][i%40] = locb[(size_t)(q0 + i/40)*40 + i%40];
  __syncthreads();
  float acc0[16] = {}, acc1[16] = {};
  const float* W = Wcomb + (size_t)l*40*EE;
#pragma unroll 8
  for (int f = 0; f < 40; ++f) {
    float wa = W[(size_t)f*EE + t];
    float wb = W[(size_t)f*EE + t + 256];
#pragma unroll
    for (int q = 0; q < 16; ++q) {
      acc0[q] += lb[q][f]*wa;
      acc1[q] += lb[q][f]*wb;
    }
  }
  float b0 = bcomb[(size_t)l*EE + t], b1 = bcomb[(size_t)l*EE + t + 256];
  u16* dst = Lc + (size_t)l*PEs + (size_t)q0*EE;
#pragma unroll
  for (int q = 0; q < 16; ++q) {
    dst[(size_t)q*EE + t]       = f2bf(acc0[q] + b0);
    dst[(size_t)q*EE + t + 256] = f2bf(acc1[q] + b1);
  }
}

// ---- bu/td weights -> bf16 with w2/w3 folded ------------------------------
__global__ __launch_bounds__(256) void k_wconv(const float* __restrict__ buw,
    const float* __restrict__ tdw, const float* w2p, const float* w3p,
    u16* __restrict__ Wbu, u16* __restrict__ Wtd) {
  int gid = blockIdx.x*256 + threadIdx.x;
  int which = blockIdx.y;
  int k8 = gid & 63;
  int row = gid >> 6;
  const float* src = (which ? tdw : buw) + (size_t)row*FANC + k8*8;
  float s = which ? *w3p : *w2p;
  u16* dst = (which ? Wtd : Wbu) + (size_t)row*EE + k8*8;
  short8v o;
#pragma unroll
  for (int j = 0; j < 8; ++j) o[j] = (short)f2bf(s*src[j]);
  *(short8v*)dst = o;
}

// ---- conv weights [512][192] f32 -> bf16 ----------------------------------
__global__ __launch_bounds__(256) void k_wcv(const float* __restrict__ cw,
                                             u16* __restrict__ Wc) {
  size_t i = ((size_t)blockIdx.x*256 + threadIdx.x)*8;   // 98304 total
  short8v o;
#pragma unroll
  for (int j = 0; j < 8; ++j) o[j] = (short)f2bf(cw[i + j]);
  *(short8v*)(Wc + i) = o;
}

// ---- im2col: x [8][3][256][256] f32 -> Apat [8192][192] bf16 ---------------
__global__ __launch_bounds__(256) void k_im2col(const float* __restrict__ x,
                                                u16* __restrict__ Apat) {
  int t = threadIdx.x;
  int R = blockIdx.x*8 + (t >> 5);        // 0..6143 = (b*3+c)*256 + h8
  int wtok = t & 31;
  int b = R / 768, rem = R - b*768, c = rem >> 8, h8 = rem & 255;
  int h = h8 >> 3, kh = h8 & 7;
  const float* src = x + (size_t)R*256 + wtok*8;
  float4 v0 = *(const float4*)src, v1 = *(const float4*)(src + 4);
  short8v o;
  o[0]=(short)f2bf(v0.x); o[1]=(short)f2bf(v0.y); o[2]=(short)f2bf(v0.z); o[3]=(short)f2bf(v0.w);
  o[4]=(short)f2bf(v1.x); o[5]=(short)f2bf(v1.y); o[6]=(short)f2bf(v1.z); o[7]=(short)f2bf(v1.w);
  int n = b*1024 + h*32 + wtok;
  *(short8v*)(Apat + (size_t)n*KC + c*64 + kh*8) = o;
}

// ---- conv GEMM: Bpre[0][n][e] = Apat @ Wc^T + cb, + statsA -----------------
__global__ __launch_bounds__(256) void k_cgemm(const u16* __restrict__ Apat,
    const u16* __restrict__ Wc, const float* __restrict__ cb,
    u16* __restrict__ Obf, float* __restrict__ statsA) {
  __shared__ char As[16384];
  __shared__ char Bs[16384];
  int tid = threadIdx.x, lane = tid & 63;
  int wbu = __builtin_amdgcn_readfirstlane(tid & ~63);
  int w = wbu >> 6, wr = w & 1, wc = w >> 1, lo = lane & 15, g = lane >> 4;
  int n0 = blockIdx.x*128, e0 = blockIdx.y*128;
  f32x4 acc[4][4] = {};
  gemm128(Apat + (size_t)n0*KC, KC, Wc + (size_t)e0*KC, KC, 3, As, Bs, wbu, lane, acc);
  float stS[4] = {}, stQ[4] = {};
#pragma unroll
  for (int m = 0; m < 4; ++m)
#pragma unroll
    for (int n = 0; n < 4; ++n) {
      int e = e0 + wc*64 + n*16 + lo;
      float bias = cb[e];
#pragma unroll
      for (int r = 0; r < 4; ++r) {
        int row = n0 + wr*64 + m*16 + g*4 + r;
        float v = acc[m][n][r] + bias;
        Obf[(size_t)row*EE + e] = f2bf(v);
        stS[n] += v; stQ[n] += v*v;
      }
    }
#pragma unroll
  for (int n = 0; n < 4; ++n) {
    float s = stS[n], q2 = stQ[n];
    s  += __shfl_xor(s, 16);  s  += __shfl_xor(s, 32);
    q2 += __shfl_xor(q2, 16); q2 += __shfl_xor(q2, 32);
    if (g == 0) {
      int e = e0 + wc*64 + n*16 + lo;
      atomicAdd(&statsA[e], s);
      atomicAdd(&statsA[EE + e], q2);
    }
  }
}

// ---- BN apply (stats inline) + bf16 + transposed bf16 ----------------------
__global__ __launch_bounds__(256) void k_bnx(const u16* __restrict__ Xh,
    const float* __restrict__ stats, const float* __restrict__ gam,
    const float* __restrict__ bta, u16* __restrict__ Bpost,
    u16* __restrict__ XbfT) {
  __shared__ u16 tile[32][34];
  __shared__ float ssl[2][32];
  int b = blockIdx.z;
  int p0 = blockIdx.x * 32, e0 = blockIdx.y * 32;
  int tr = threadIdx.x >> 5, tc = threadIdx.x & 31;
  if (threadIdx.x < 32) {
    int c = e0 + threadIdx.x;
    float mean = stats[c] * (1.f/8192.f);
    float var  = stats[EE + c] * (1.f/8192.f) - mean*mean;
    var = fmaxf(var, 0.f);
    float sc = gam[c] * rsqrtf(var + EPS_F);
    ssl[0][threadIdx.x] = sc;
    ssl[1][threadIdx.x] = bta[c] - mean*sc;
  }
  __syncthreads();
  float sc = ssl[0][tc], sh = ssl[1][tc];
#pragma unroll
  for (int i = 0; i < 4; ++i) {
    int p = tr + 8*i;
    size_t idx = (size_t)(b*PP + p0 + p)*EE + e0 + tc;
    u16 us = f2bf(bf2f(Xh[idx])*sc + sh);
    Bpost[idx] = us;
    tile[p][tc] = us;
  }
  __syncthreads();
#pragma unroll
  for (int i = 0; i < 4; ++i) {
    int e = tr + 8*i;
    XbfT[(size_t)(b*EE + e0 + e)*PP + p0 + tc] = tile[tc][e];
  }
}

// ---- GEMM1: P = exp(beta * X X^T) per batch, + denom atomics ---------------
__global__ __launch_bounds__(256) void k_gemm1(const u16* __restrict__ Xb,
    u16* __restrict__ P, float* __restrict__ denom) {
  __shared__ char As[16384];
  __shared__ char Bs[16384];
  int tid = threadIdx.x, lane = tid & 63;
  int wbu = __builtin_amdgcn_readfirstlane(tid & ~63);
  int w = wbu >> 6, wr = w & 1, wc = w >> 1, lo = lane & 15, g = lane >> 4;
  int q0 = blockIdx.x*128, k0 = blockIdx.y*128, b = blockIdx.z;
  f32x4 acc[4][4] = {};
  gemm128(Xb + ((size_t)(b*PP + q0))*EE, EE, Xb + ((size_t)(b*PP + k0))*EE, EE,
          8, As, Bs, wbu, lane, acc);
  float rs[4][4] = {};   // [m][r]
#pragma unroll
  for (int m = 0; m < 4; ++m)
#pragma unroll
    for (int n = 0; n < 4; ++n)
#pragma unroll
      for (int r = 0; r < 4; ++r) {
        float ex = __expf(BETA_F * acc[m][n][r]);
        rs[m][r] += ex;
        int q = q0 + wr*64 + m*16 + g*4 + r;
        int k = k0 + wc*64 + n*16 + lo;
        P[((size_t)(b*PP) + q)*PP + k] = f2bf(ex);
      }
#pragma unroll
  for (int m = 0; m < 4; ++m)
#pragma unroll
    for (int r = 0; r < 4; ++r) {
      float v = rs[m][r];
      v += __shfl_xor(v, 1); v += __shfl_xor(v, 2);
      v += __shfl_xor(v, 4); v += __shfl_xor(v, 8);
      if (lo == 0) atomicAdd(&denom[q0 + wr*64 + m*16 + g*4 + r], v);
    }
}

// ---- mega GEMM: O = PV*w4/denom + bu + td + w1*Xbn + Lcomb -----------------
template<int ACCST>
__global__ __launch_bounds__(256) void k_mega(
    const u16* aBu, const u16* bBu, int stBu,
    const u16* aTd, const u16* bTd, int stTd,
    const u16* __restrict__ Pm, const u16* __restrict__ Vt,
    const u16* __restrict__ Xh, const u16* __restrict__ Lc,
    const float* __restrict__ w1p, const float* __restrict__ w4p,
    const float* __restrict__ denom, float* __restrict__ statsB,
    u16* __restrict__ Obf) {
  __shared__ char As[16384];
  __shared__ char Bs[16384];
  int tid = threadIdx.x, lane = tid & 63;
  int wbu = __builtin_amdgcn_readfirstlane(tid & ~63);
  int w = wbu >> 6, wr = w & 1, wc = w >> 1, lo = lane & 15, g = lane >> 4;
  int n0 = blockIdx.x*128, e0 = blockIdx.y*128;
  int b = blockIdx.x >> 3;
  f32x4 acc[4][4] = {};
  // PV first, then scale by w4/denom in registers
  gemm128(Pm + (size_t)n0*PP, PP, Vt + (size_t)b*EE*PP + (size_t)e0*PP, PP, 16,
          As, Bs, wbu, lane, acc);
  float w4 = *w4p;
#pragma unroll
  for (int m = 0; m < 4; ++m)
#pragma unroll
    for (int r = 0; r < 4; ++r) {
      int q = (n0 + wr*64 + m*16 + g*4 + r) & 1023;
      float s = w4 / denom[q];
#pragma unroll
      for (int n = 0; n < 4; ++n) acc[m][n][r] *= s;
    }
  if (stBu) gemm128(aBu + (size_t)n0*EE, EE, bBu + (size_t)e0*EE, EE, 8, As, Bs, wbu, lane, acc);
  if (stTd) gemm128(aTd + (size_t)n0*EE, EE, bTd + (size_t)e0*EE, EE, 8, As, Bs, wbu, lane, acc);
  float w1 = *w1p;
  float stS[4] = {}, stQ[4] = {};
#pragma unroll
  for (int m = 0; m < 4; ++m)
#pragma unroll
    for (int n = 0; n < 4; ++n)
#pragma unroll
      for (int r = 0; r < 4; ++r) {
        int nn = n0 + wr*64 + m*16 + g*4 + r;
        int e = e0 + wc*64 + n*16 + lo;
        size_t idx = (size_t)nn*EE + e;
        float v = acc[m][n][r] + w1*bf2f(Xh[idx]) + bf2f(Lc[(size_t)(nn & 1023)*EE + e]);
        Obf[idx] = f2bf(v);
        if (ACCST) { stS[n] += v; stQ[n] += v*v; }
      }
  if (ACCST) {
#pragma unroll
    for (int n = 0; n < 4; ++n) {
      float s = stS[n], q2 = stQ[n];
      s  += __shfl_xor(s, 16);  s  += __shfl_xor(s, 32);
      q2 += __shfl_xor(q2, 16); q2 += __shfl_xor(q2, 32);
      if (g == 0) {
        int e = e0 + wc*64 + n*16 + lo;
        atomicAdd(&statsB[e], s);
        atomicAdd(&statsB[EE + e], q2);
      }
    }
  }
}

// ---- final transpose: Bpre bf16 [l][b][hw][e] -> out f32 [b][e][hw][5] -----
__global__ __launch_bounds__(256) void k_transpose_bf(const u16* __restrict__ Bpre,
                                                      float* __restrict__ out) {
  __shared__ u16 tile[5][32][34];
  int t = threadIdx.x;
  int hw0 = blockIdx.x * 32, e0 = blockIdx.y * 32, b = blockIdx.z;
  int tr = t >> 5, tc = t & 31;
#pragma unroll
  for (int l = 0; l < 5; ++l) {
    const u16* src = Bpre + (size_t)l*NEs + ((size_t)(b*PP + hw0))*EE + e0;
    for (int p = 0; p < 4; ++p)
      tile[l][tr + 8*p][tc] = src[(size_t)(tr + 8*p)*EE + tc];
  }
  __syncthreads();
  for (int p = 0; p < 4; ++p) {
    int e = tr + 8*p;
    float* dst = out + (((size_t)(b*EE + e0 + e))*PP + (size_t)(hw0 + tc))*5;
#pragma unroll
    for (int l = 0; l < 5; ++l) dst[l] = bf2f(tile[l][tc][e]);
  }
}

// ---------------------------------------------------------------------------
extern "C" void kernel_launch(void* const* d_in, const int* in_sizes, int n_in,
                              void* d_out, int out_size, void* d_ws, size_t ws_size,
                              hipStream_t stream) {
  const float* x     = (const float*)d_in[0];
  const float* convw = (const float*)d_in[1];
  const float* convb = (const float*)d_in[2];
  const float* bu_w  = (const float*)d_in[3];
  const float* bu_b  = (const float*)d_in[4];
  const float* td_w  = (const float*)d_in[5];
  const float* td_b  = (const float*)d_in[6];
  const float* bn_g  = (const float*)d_in[7];
  const float* bn_b  = (const float*)d_in[8];
  const float* w1 = (const float*)d_in[9];
  const float* w2 = (const float*)d_in[10];
  const float* w3 = (const float*)d_in[11];
  const float* w4 = (const float*)d_in[12];
  float* out = (float*)d_out;

  // ws layout
  u16* Bpre  = (u16*)d_ws;                      // 5*NE  (state; final emb)
  u16* Bpost = Bpre + 5*NEs;                    // 2*NE  (rotating post-BN)
  u16* P     = Bpost + 2*NEs;                   // NT*PP
  u16* XbfT  = P + SEs;                         // NE    ([b][e][p])
  u16* Lcomb = XbfT + NEs;                      // 5*PE
  u16* Wbu_s = Lcomb + 5*PEs;                   // 5*512*512
  u16* Wtd_s = Wbu_s + (size_t)5*EE*EE;         // 5*512*512
  u16* Apat  = Wtd_s + (size_t)5*EE*EE;         // 8192*192 (im2col)
  u16* Wcv   = Apat + (size_t)NT*KC;            // 512*192
  float* locb   = (float*)(Wcv + (size_t)EE*KC);      // 40960
  float* Wcomb  = locb + 40960;                 // 5*40*512
  float* bcomb  = Wcomb + 102400;               // 2560
  float* statsA = bcomb + 2560;                 // 5*1024
  float* statsB = statsA + 5*1024;              // 5*1024
  float* denomAll = statsB + 5*1024;            // 10*1024
  // ~98 MB total

  // ---- setup ----
  k_locb<<<4, 256, 0, stream>>>(locb);
  k_wcombT<<<dim3(5, 8), 256, 0, stream>>>(bu_w, bu_b, td_w, td_b, w2, w3, Wcomb, bcomb);
  k_loccomb2<<<dim3(5, 64), 256, 0, stream>>>(locb, Wcomb, bcomb, Lcomb);
  k_wconv<<<dim3(640, 2), 256, 0, stream>>>(bu_w, td_w, w2, w3, Wbu_s, Wtd_s);
  k_wcv<<<48, 256, 0, stream>>>(convw, Wcv);
  k_im2col<<<768, 256, 0, stream>>>(x, Apat);
  hipMemsetAsync(Bpre + NEs, 0, 4*NEs*sizeof(u16), stream);       // levels 1..4 = 0
  hipMemsetAsync(statsA, 0, (5*1024 + 5*1024 + 10*1024)*sizeof(float), stream);
  k_cgemm<<<dim3(64, 4), 256, 0, stream>>>(Apat, Wcv, convb, Bpre, statsA);

  for (int cyc = 0; cyc < 2; ++cyc) {
    for (int l = 0; l < 5; ++l) {
      const float* statsSel = (cyc == 0 ? statsA : statsB) + (size_t)l*1024;
      u16* BpostL = Bpost + (size_t)(l & 1)*NEs;
      k_bnx<<<dim3(32,16,8), 256, 0, stream>>>(Bpre + (size_t)l*NEs, statsSel,
          bn_g + (size_t)l*EE, bn_b + (size_t)l*EE, BpostL, XbfT);
      float* dnm = denomAll + (size_t)(cyc*5 + l)*1024;
      k_gemm1<<<dim3(8,8,8), 256, 0, stream>>>(BpostL, P, dnm);
      const u16* aBu = (l > 0) ? Bpost + (size_t)((l-1) & 1)*NEs : nullptr;
      const u16* bBu = (l > 0) ? Wbu_s + (size_t)l*EE*EE : nullptr;
      const u16* aTd = (l < 4) ? Bpre + (size_t)(l+1)*NEs : nullptr;
      const u16* bTd = (l < 4) ? Wtd_s + (size_t)l*EE*EE : nullptr;
      if (cyc == 0)
        k_mega<1><<<dim3(64,4), 256, 0, stream>>>(aBu, bBu, (l>0)?1:0,
            aTd, bTd, (l<4)?1:0, P, XbfT, BpostL, Lcomb + (size_t)l*PEs,
            w1, w4, dnm, statsB + (size_t)l*1024, Bpre + (size_t)l*NEs);
      else
        k_mega<0><<<dim3(64,4), 256, 0, stream>>>(aBu, bBu, (l>0)?1:0,
            aTd, bTd, (l<4)?1:0, P, XbfT, BpostL, Lcomb + (size_t)l*PEs,
            w1, w4, dnm, nullptr, Bpre + (size_t)l*NEs);
    }
  }
  k_transpose_bf<<<dim3(32,16,8), 256, 0, stream>>>(Bpre, out);
}

// Round 6
// 532.971 us; speedup vs baseline: 21.0177x; 1.4788x over previous
//
#include <hip/hip_runtime.h>

// ---------------------------------------------------------------------------
// GLOM forward. Round 6: level-batched passes (3 launches/cycle), double-
// buffered bf16 state; all GEMMs 128x128 MFMA tiles w/ global_load_lds.
// B=8, H=W=32, P=1024, N=8192 tokens, E=512, LF=10, FAN=552.
// ---------------------------------------------------------------------------

#define PI_F 3.14159265358979323846f

static constexpr int   PP    = 1024;
static constexpr int   NT    = 8192;
static constexpr int   EE    = 512;
static constexpr int   FANC  = 552;
static constexpr int   KC    = 192;
static constexpr float BETA_F = 0.001f;
static constexpr float EPS_F  = 1e-5f;
static constexpr size_t NEs = (size_t)NT * EE;   // 4,194,304
static constexpr size_t PEs = (size_t)PP * EE;   //   524,288
static constexpr size_t SEs = (size_t)NT * PP;   // 8,388,608 (per-level P)

typedef __attribute__((ext_vector_type(8))) short short8v;  // 8 bf16
typedef __attribute__((ext_vector_type(4))) float f32x4;
typedef unsigned short u16;

__device__ __forceinline__ u16 f2bf(float x) {
  unsigned u = __float_as_uint(x);
  return (u16)((u + (((u >> 16) & 1u) + 0x7fffu)) >> 16);   // RNE
}
__device__ __forceinline__ float bf2f(u16 h) {
  return __uint_as_float(((unsigned)h) << 16);
}

__device__ __forceinline__ void gll16(const u16* g, u16* l) {
  __builtin_amdgcn_global_load_lds(
      (const __attribute__((address_space(1))) unsigned int*)g,
      (__attribute__((address_space(3))) unsigned int*)l, 16, 0, 0);
}

// swizzled LDS read: tile row-major [rows][64] bf16 (128B rows), chunk cb 0..7
__device__ __forceinline__ short8v ldsrd(const char* base, int row, int cb) {
  return *(const short8v*)(base + row*128 + (((cb ^ (row & 7)) << 4)));
}

// ---- 128x128 GEMM segment: C += A(128xK) * B(128xK)^T ---------------------
__device__ __forceinline__ void gemm128(
    const u16* __restrict__ Ab, int aStr,
    const u16* __restrict__ Bb, int bStr,
    int nsteps, char* As, char* Bs, int wbu, int lane, f32x4 (&acc)[4][4]) {
  int w = wbu >> 6, wr = w & 1, wc = w >> 1, lo = lane & 15, g = lane >> 4;
  for (int st = 0; st < nsteps; ++st) {
    int kk = st * 64;
    __syncthreads();
#pragma unroll
    for (int j = 0; j < 4; ++j) {
      int i = j*256 + wbu + lane;
      int r = i >> 3, c = (i & 7) ^ (r & 7);
      gll16(Ab + (size_t)r*aStr + kk + c*8, (u16*)(As + (j*256 + wbu)*16));
    }
#pragma unroll
    for (int j = 0; j < 4; ++j) {
      int i = j*256 + wbu + lane;
      int r = i >> 3, c = (i & 7) ^ (r & 7);
      gll16(Bb + (size_t)r*bStr + kk + c*8, (u16*)(Bs + (j*256 + wbu)*16));
    }
    __syncthreads();
#pragma unroll
    for (int h = 0; h < 2; ++h) {
      int cb = h*4 + g;
      short8v a[4], b[4];
#pragma unroll
      for (int m = 0; m < 4; ++m) a[m] = ldsrd(As, wr*64 + m*16 + lo, cb);
#pragma unroll
      for (int n = 0; n < 4; ++n) b[n] = ldsrd(Bs, wc*64 + n*16 + lo, cb);
#pragma unroll
      for (int m = 0; m < 4; ++m)
#pragma unroll
        for (int n = 0; n < 4; ++n)
          acc[m][n] = __builtin_amdgcn_mfma_f32_16x16x32_bf16(a[m], b[n], acc[m][n], 0, 0, 0);
    }
  }
}

// ---------------- positional-encoding table [P,40] --------------------------
__global__ void k_locb(float* __restrict__ locb) {
  int q = blockIdx.x * blockDim.x + threadIdx.x;
  if (q >= PP) return;
  int h = q >> 5, w = q & 31;
  float ph = 2.f * (float)h / 32.f - 1.f;
  float pw = 2.f * (float)w / 32.f - 1.f;
  float* d = locb + (size_t)q * 40;
#pragma unroll
  for (int j = 0; j < 10; ++j) {
    float f = (float)(1 << j) * PI_F;
    float ah = f * ph, aw = f * pw;
    d[2*j]     = sinf(ah); d[2*j+1]  = cosf(ah);
    d[20+2*j]  = sinf(aw); d[21+2*j] = cosf(aw);
  }
}

// ---- Wcomb[l][f][e], bcomb[l][e]: one pass over scattered weight layout ----
__global__ __launch_bounds__(256) void k_wcombT(
    const float* __restrict__ buw, const float* __restrict__ bub,
    const float* __restrict__ tdw, const float* __restrict__ tdb,
    const float* w2p, const float* w3p,
    float* __restrict__ Wcomb, float* __restrict__ bcomb) {
  int l = blockIdx.x, et = blockIdx.y, t = threadIdx.x;
  int e = et*64 + (t >> 2), fg = (t & 3)*10;
  float w2 = *w2p, w3 = *w3p;
  const float* bu = buw + ((size_t)l*EE + e)*FANC + EE;
  const float* td = tdw + ((size_t)l*EE + e)*FANC + EE;
#pragma unroll
  for (int j = 0; j < 10; ++j) {
    int f = fg + j;
    float v = 0.f;
    if (l > 0) v += w2 * bu[f];
    if (l < 4) v += w3 * td[f];
    Wcomb[((size_t)l*40 + f)*EE + e] = v;
  }
  if (fg == 0) {
    float bv = 0.f;
    if (l > 0) bv += w2 * bub[(size_t)l*EE + e];
    if (l < 4) bv += w3 * tdb[(size_t)l*EE + e];
    bcomb[(size_t)l*EE + e] = bv;
  }
}

// ---- Lcomb[l][q][e] via coalesced Wcomb, 16-q register blocking ------------
__global__ __launch_bounds__(256) void k_loccomb2(const float* __restrict__ locb,
    const float* __restrict__ Wcomb, const float* __restrict__ bcomb,
    u16* __restrict__ Lc) {
  int l = blockIdx.x, q0 = blockIdx.y * 16, t = threadIdx.x;
  __shared__ float lb[16][40];
  for (int i = t; i < 640; i += 256) lb[i/40][i%40] = locb[(size_t)(q0 + i/40)*40 + i%40];
  __syncthreads();
  float acc0[16] = {}, acc1[16] = {};
  const float* W = Wcomb + (size_t)l*40*EE;
#pragma unroll 8
  for (int f = 0; f < 40; ++f) {
    float wa = W[(size_t)f*EE + t];
    float wb = W[(size_t)f*EE + t + 256];
#pragma unroll
    for (int q = 0; q < 16; ++q) {
      acc0[q] += lb[q][f]*wa;
      acc1[q] += lb[q][f]*wb;
    }
  }
  float b0 = bcomb[(size_t)l*EE + t], b1 = bcomb[(size_t)l*EE + t + 256];
  u16* dst = Lc + (size_t)l*PEs + (size_t)q0*EE;
#pragma unroll
  for (int q = 0; q < 16; ++q) {
    dst[(size_t)q*EE + t]       = f2bf(acc0[q] + b0);
    dst[(size_t)q*EE + t + 256] = f2bf(acc1[q] + b1);
  }
}

// ---- bu/td weights -> bf16 with w2/w3 folded ------------------------------
__global__ __launch_bounds__(256) void k_wconv(const float* __restrict__ buw,
    const float* __restrict__ tdw, const float* w2p, const float* w3p,
    u16* __restrict__ Wbu, u16* __restrict__ Wtd) {
  int gid = blockIdx.x*256 + threadIdx.x;
  int which = blockIdx.y;
  int k8 = gid & 63;
  int row = gid >> 6;
  const float* src = (which ? tdw : buw) + (size_t)row*FANC + k8*8;
  float s = which ? *w3p : *w2p;
  u16* dst = (which ? Wtd : Wbu) + (size_t)row*EE + k8*8;
  short8v o;
#pragma unroll
  for (int j = 0; j < 8; ++j) o[j] = (short)f2bf(s*src[j]);
  *(short8v*)dst = o;
}

// ---- conv weights [512][192] f32 -> bf16 ----------------------------------
__global__ __launch_bounds__(256) void k_wcv(const float* __restrict__ cw,
                                             u16* __restrict__ Wc) {
  size_t i = ((size_t)blockIdx.x*256 + threadIdx.x)*8;
  short8v o;
#pragma unroll
  for (int j = 0; j < 8; ++j) o[j] = (short)f2bf(cw[i + j]);
  *(short8v*)(Wc + i) = o;
}

// ---- im2col: x [8][3][256][256] f32 -> Apat [8192][192] bf16 ---------------
__global__ __launch_bounds__(256) void k_im2col(const float* __restrict__ x,
                                                u16* __restrict__ Apat) {
  int t = threadIdx.x;
  int R = blockIdx.x*8 + (t >> 5);
  int wtok = t & 31;
  int b = R / 768, rem = R - b*768, c = rem >> 8, h8 = rem & 255;
  int h = h8 >> 3, kh = h8 & 7;
  const float* src = x + (size_t)R*256 + wtok*8;
  float4 v0 = *(const float4*)src, v1 = *(const float4*)(src + 4);
  short8v o;
  o[0]=(short)f2bf(v0.x); o[1]=(short)f2bf(v0.y); o[2]=(short)f2bf(v0.z); o[3]=(short)f2bf(v0.w);
  o[4]=(short)f2bf(v1.x); o[5]=(short)f2bf(v1.y); o[6]=(short)f2bf(v1.z); o[7]=(short)f2bf(v1.w);
  int n = b*1024 + h*32 + wtok;
  *(short8v*)(Apat + (size_t)n*KC + c*64 + kh*8) = o;
}

// ---- conv GEMM: BpreA[0][n][e] = Apat @ Wc^T + cb, + statsA ----------------
__global__ __launch_bounds__(256) void k_cgemm(const u16* __restrict__ Apat,
    const u16* __restrict__ Wc, const float* __restrict__ cb,
    u16* __restrict__ Obf, float* __restrict__ statsA) {
  __shared__ char As[16384];
  __shared__ char Bs[16384];
  int tid = threadIdx.x, lane = tid & 63;
  int wbu = __builtin_amdgcn_readfirstlane(tid & ~63);
  int w = wbu >> 6, wr = w & 1, wc = w >> 1, lo = lane & 15, g = lane >> 4;
  int n0 = blockIdx.x*128, e0 = blockIdx.y*128;
  f32x4 acc[4][4] = {};
  gemm128(Apat + (size_t)n0*KC, KC, Wc + (size_t)e0*KC, KC, 3, As, Bs, wbu, lane, acc);
  float stS[4] = {}, stQ[4] = {};
#pragma unroll
  for (int m = 0; m < 4; ++m)
#pragma unroll
    for (int n = 0; n < 4; ++n) {
      int e = e0 + wc*64 + n*16 + lo;
      float bias = cb[e];
#pragma unroll
      for (int r = 0; r < 4; ++r) {
        int row = n0 + wr*64 + m*16 + g*4 + r;
        float v = acc[m][n][r] + bias;
        Obf[(size_t)row*EE + e] = f2bf(v);
        stS[n] += v; stQ[n] += v*v;
      }
    }
#pragma unroll
  for (int n = 0; n < 4; ++n) {
    float s = stS[n], q2 = stQ[n];
    s  += __shfl_xor(s, 16);  s  += __shfl_xor(s, 32);
    q2 += __shfl_xor(q2, 16); q2 += __shfl_xor(q2, 32);
    if (g == 0) {
      int e = e0 + wc*64 + n*16 + lo;
      atomicAdd(&statsA[e], s);
      atomicAdd(&statsA[EE + e], q2);
    }
  }
}

// ---- BN apply, all levels: z = l*8+b ---------------------------------------
__global__ __launch_bounds__(256) void k_bnx(const u16* __restrict__ BpreCur,
    const float* __restrict__ statsBase, const float* __restrict__ gam,
    const float* __restrict__ bta, u16* __restrict__ BpostAll,
    u16* __restrict__ XbfTAll) {
  __shared__ u16 tile[32][34];
  __shared__ float ssl[2][32];
  int l = blockIdx.z >> 3, b = blockIdx.z & 7;
  int p0 = blockIdx.x * 32, e0 = blockIdx.y * 32;
  int tr = threadIdx.x >> 5, tc = threadIdx.x & 31;
  const float* stats = statsBase + (size_t)l*1024;
  if (threadIdx.x < 32) {
    int c = e0 + threadIdx.x;
    float mean = stats[c] * (1.f/8192.f);
    float var  = stats[EE + c] * (1.f/8192.f) - mean*mean;
    var = fmaxf(var, 0.f);
    float sc = gam[(size_t)l*EE + c] * rsqrtf(var + EPS_F);
    ssl[0][threadIdx.x] = sc;
    ssl[1][threadIdx.x] = bta[(size_t)l*EE + c] - mean*sc;
  }
  __syncthreads();
  float sc = ssl[0][tc], sh = ssl[1][tc];
  const u16* Xh = BpreCur + (size_t)l*NEs;
  u16* Bpost = BpostAll + (size_t)l*NEs;
  u16* XbfT  = XbfTAll + (size_t)l*NEs;
#pragma unroll
  for (int i = 0; i < 4; ++i) {
    int p = tr + 8*i;
    size_t idx = (size_t)(b*PP + p0 + p)*EE + e0 + tc;
    u16 us = f2bf(bf2f(Xh[idx])*sc + sh);
    Bpost[idx] = us;
    tile[p][tc] = us;
  }
  __syncthreads();
#pragma unroll
  for (int i = 0; i < 4; ++i) {
    int e = tr + 8*i;
    XbfT[(size_t)(b*EE + e0 + e)*PP + p0 + tc] = tile[tc][e];
  }
}

// ---- GEMM1 all levels: P[l] = exp(beta * X X^T), denom atomics; z=l*8+b ----
__global__ __launch_bounds__(256) void k_gemm1(const u16* __restrict__ BpostAll,
    u16* __restrict__ PAll, float* __restrict__ denomCyc) {
  __shared__ char As[16384];
  __shared__ char Bs[16384];
  int tid = threadIdx.x, lane = tid & 63;
  int wbu = __builtin_amdgcn_readfirstlane(tid & ~63);
  int w = wbu >> 6, wr = w & 1, wc = w >> 1, lo = lane & 15, g = lane >> 4;
  int l = blockIdx.z >> 3, b = blockIdx.z & 7;
  int q0 = blockIdx.x*128, k0 = blockIdx.y*128;
  const u16* Xb = BpostAll + (size_t)l*NEs;
  u16* P = PAll + (size_t)l*SEs;
  float* denom = denomCyc + (size_t)l*1024;
  f32x4 acc[4][4] = {};
  gemm128(Xb + ((size_t)(b*PP + q0))*EE, EE, Xb + ((size_t)(b*PP + k0))*EE, EE,
          8, As, Bs, wbu, lane, acc);
  float rs[4][4] = {};
#pragma unroll
  for (int m = 0; m < 4; ++m)
#pragma unroll
    for (int n = 0; n < 4; ++n)
#pragma unroll
      for (int r = 0; r < 4; ++r) {
        float ex = __expf(BETA_F * acc[m][n][r]);
        rs[m][r] += ex;
        int q = q0 + wr*64 + m*16 + g*4 + r;
        int k = k0 + wc*64 + n*16 + lo;
        P[((size_t)(b*PP) + q)*PP + k] = f2bf(ex);
      }
#pragma unroll
  for (int m = 0; m < 4; ++m)
#pragma unroll
    for (int r = 0; r < 4; ++r) {
      float v = rs[m][r];
      v += __shfl_xor(v, 1); v += __shfl_xor(v, 2);
      v += __shfl_xor(v, 4); v += __shfl_xor(v, 8);
      if (lo == 0) atomicAdd(&denom[q0 + wr*64 + m*16 + g*4 + r], v);
    }
}

// ---- mega all levels: O[l] = PV*w4/denom + bu + td + w1*Xbn + Lcomb; z=l ---
template<int ACCST>
__global__ __launch_bounds__(256) void k_mega(
    const u16* __restrict__ BpostAll, const u16* __restrict__ BpreCur,
    const u16* __restrict__ PAll, const u16* __restrict__ XbfTAll,
    const u16* __restrict__ WbuAll, const u16* __restrict__ WtdAll,
    const u16* __restrict__ LcAll,
    const float* __restrict__ w1p, const float* __restrict__ w4p,
    const float* __restrict__ denomCyc, float* __restrict__ statsB,
    u16* __restrict__ BpreNext) {
  __shared__ char As[16384];
  __shared__ char Bs[16384];
  int tid = threadIdx.x, lane = tid & 63;
  int wbu = __builtin_amdgcn_readfirstlane(tid & ~63);
  int w = wbu >> 6, wr = w & 1, wc = w >> 1, lo = lane & 15, g = lane >> 4;
  int l = blockIdx.z;
  int n0 = blockIdx.x*128, e0 = blockIdx.y*128;
  int b = blockIdx.x >> 3;
  const float* denom = denomCyc + (size_t)l*1024;
  f32x4 acc[4][4] = {};
  // PV first, then scale by w4/denom in registers
  gemm128(PAll + (size_t)l*SEs + (size_t)n0*PP, PP,
          XbfTAll + (size_t)l*NEs + (size_t)b*EE*PP + (size_t)e0*PP, PP, 16,
          As, Bs, wbu, lane, acc);
  float w4 = *w4p;
#pragma unroll
  for (int m = 0; m < 4; ++m)
#pragma unroll
    for (int r = 0; r < 4; ++r) {
      int q = (n0 + wr*64 + m*16 + g*4 + r) & 1023;
      float s = w4 / denom[q];
#pragma unroll
      for (int n = 0; n < 4; ++n) acc[m][n][r] *= s;
    }
  if (l > 0)
    gemm128(BpostAll + (size_t)(l-1)*NEs + (size_t)n0*EE, EE,
            WbuAll + (size_t)l*EE*EE + (size_t)e0*EE, EE, 8, As, Bs, wbu, lane, acc);
  if (l < 4)
    gemm128(BpreCur + (size_t)(l+1)*NEs + (size_t)n0*EE, EE,
            WtdAll + (size_t)l*EE*EE + (size_t)e0*EE, EE, 8, As, Bs, wbu, lane, acc);
  float w1 = *w1p;
  const u16* Xh = BpostAll + (size_t)l*NEs;
  const u16* Lc = LcAll + (size_t)l*PEs;
  u16* Obf = BpreNext + (size_t)l*NEs;
  float stS[4] = {}, stQ[4] = {};
#pragma unroll
  for (int m = 0; m < 4; ++m)
#pragma unroll
    for (int n = 0; n < 4; ++n)
#pragma unroll
      for (int r = 0; r < 4; ++r) {
        int nn = n0 + wr*64 + m*16 + g*4 + r;
        int e = e0 + wc*64 + n*16 + lo;
        size_t idx = (size_t)nn*EE + e;
        float v = acc[m][n][r] + w1*bf2f(Xh[idx]) + bf2f(Lc[(size_t)(nn & 1023)*EE + e]);
        Obf[idx] = f2bf(v);
        if (ACCST) { stS[n] += v; stQ[n] += v*v; }
      }
  if (ACCST) {
#pragma unroll
    for (int n = 0; n < 4; ++n) {
      float s = stS[n], q2 = stQ[n];
      s  += __shfl_xor(s, 16);  s  += __shfl_xor(s, 32);
      q2 += __shfl_xor(q2, 16); q2 += __shfl_xor(q2, 32);
      if (g == 0) {
        int e = e0 + wc*64 + n*16 + lo;
        atomicAdd(&statsB[(size_t)l*1024 + e], s);
        atomicAdd(&statsB[(size_t)l*1024 + EE + e], q2);
      }
    }
  }
}

// ---- final transpose: Bpre bf16 [l][b][hw][e] -> out f32 [b][e][hw][5] -----
__global__ __launch_bounds__(256) void k_transpose_bf(const u16* __restrict__ Bpre,
                                                      float* __restrict__ out) {
  __shared__ u16 tile[5][32][34];
  int t = threadIdx.x;
  int hw0 = blockIdx.x * 32, e0 = blockIdx.y * 32, b = blockIdx.z;
  int tr = t >> 5, tc = t & 31;
#pragma unroll
  for (int l = 0; l < 5; ++l) {
    const u16* src = Bpre + (size_t)l*NEs + ((size_t)(b*PP + hw0))*EE + e0;
    for (int p = 0; p < 4; ++p)
      tile[l][tr + 8*p][tc] = src[(size_t)(tr + 8*p)*EE + tc];
  }
  __syncthreads();
  for (int p = 0; p < 4; ++p) {
    int e = tr + 8*p;
    float* dst = out + (((size_t)(b*EE + e0 + e))*PP + (size_t)(hw0 + tc))*5;
#pragma unroll
    for (int l = 0; l < 5; ++l) dst[l] = bf2f(tile[l][tc][e]);
  }
}

// ---------------------------------------------------------------------------
extern "C" void kernel_launch(void* const* d_in, const int* in_sizes, int n_in,
                              void* d_out, int out_size, void* d_ws, size_t ws_size,
                              hipStream_t stream) {
  const float* x     = (const float*)d_in[0];
  const float* convw = (const float*)d_in[1];
  const float* convb = (const float*)d_in[2];
  const float* bu_w  = (const float*)d_in[3];
  const float* bu_b  = (const float*)d_in[4];
  const float* td_w  = (const float*)d_in[5];
  const float* td_b  = (const float*)d_in[6];
  const float* bn_g  = (const float*)d_in[7];
  const float* bn_b  = (const float*)d_in[8];
  const float* w1 = (const float*)d_in[9];
  const float* w2 = (const float*)d_in[10];
  const float* w3 = (const float*)d_in[11];
  const float* w4 = (const float*)d_in[12];
  float* out = (float*)d_out;

  // ws layout (u16 units unless noted); total ~266 MB (ws is ~320 MiB)
  u16* BpreA  = (u16*)d_ws;                    // 5*NE  cycle-0 in / cycle-1 out
  u16* BpreB  = BpreA + 5*NEs;                 // 5*NE  cycle-0 out / cycle-1 in
  u16* BpostA = BpreB + 5*NEs;                 // 5*NE  post-BN (all levels)
  u16* XbfTA  = BpostA + 5*NEs;                // 5*NE  transposed post-BN
  u16* PAll   = XbfTA + 5*NEs;                 // 5*SEs P matrices
  u16* Lcomb  = PAll + 5*SEs;                  // 5*PE
  u16* Wbu_s  = Lcomb + 5*PEs;                 // 5*512*512
  u16* Wtd_s  = Wbu_s + (size_t)5*EE*EE;       // 5*512*512
  u16* Apat   = Wtd_s + (size_t)5*EE*EE;       // 8192*192
  u16* Wcv    = Apat + (size_t)NT*KC;          // 512*192
  float* locb   = (float*)(Wcv + (size_t)EE*KC);   // 40960 f32
  float* Wcomb  = locb + 40960;                // 5*40*512
  float* bcomb  = Wcomb + 102400;              // 2560
  float* statsA = bcomb + 2560;                // 5*1024
  float* statsB = statsA + 5*1024;             // 5*1024
  float* denomAll = statsB + 5*1024;           // 10*1024

  // ---- setup ----
  k_locb<<<4, 256, 0, stream>>>(locb);
  k_wcombT<<<dim3(5, 8), 256, 0, stream>>>(bu_w, bu_b, td_w, td_b, w2, w3, Wcomb, bcomb);
  k_loccomb2<<<dim3(5, 64), 256, 0, stream>>>(locb, Wcomb, bcomb, Lcomb);
  k_wconv<<<dim3(640, 2), 256, 0, stream>>>(bu_w, td_w, w2, w3, Wbu_s, Wtd_s);
  k_wcv<<<48, 256, 0, stream>>>(convw, Wcv);
  k_im2col<<<768, 256, 0, stream>>>(x, Apat);
  hipMemsetAsync(BpreA + NEs, 0, 4*NEs*sizeof(u16), stream);   // levels 1..4 zero
  hipMemsetAsync(statsA, 0, (5*1024 + 5*1024 + 10*1024)*sizeof(float), stream);
  k_cgemm<<<dim3(64, 4), 256, 0, stream>>>(Apat, Wcv, convb, BpreA, statsA);

  for (int cyc = 0; cyc < 2; ++cyc) {
    u16* BpreCur  = (cyc == 0) ? BpreA : BpreB;
    u16* BpreNext = (cyc == 0) ? BpreB : BpreA;
    const float* statsSel = (cyc == 0) ? statsA : statsB;
    float* denomCyc = denomAll + (size_t)cyc*5*1024;
    k_bnx<<<dim3(32,16,40), 256, 0, stream>>>(BpreCur, statsSel, bn_g, bn_b,
                                              BpostA, XbfTA);
    k_gemm1<<<dim3(8,8,40), 256, 0, stream>>>(BpostA, PAll, denomCyc);
    if (cyc == 0)
      k_mega<1><<<dim3(64,4,5), 256, 0, stream>>>(BpostA, BpreCur, PAll, XbfTA,
          Wbu_s, Wtd_s, Lcomb, w1, w4, denomCyc, statsB, BpreNext);
    else
      k_mega<0><<<dim3(64,4,5), 256, 0, stream>>>(BpostA, BpreCur, PAll, XbfTA,
          Wbu_s, Wtd_s, Lcomb, w1, w4, denomCyc, nullptr, BpreNext);
  }
  k_transpose_bf<<<dim3(32,16,8), 256, 0, stream>>>(BpreA, out);
}

// Round 7
// 483.964 us; speedup vs baseline: 23.1460x; 1.1013x over previous
//
#include <hip/hip_runtime.h>

// ---------------------------------------------------------------------------
// GLOM forward. Round 7: XCD-chunked block swizzle for P/weight/V L2 locality
// in k_mega and k_gemm1 (T1). Otherwise identical to Round 6.
// B=8, H=W=32, P=1024, N=8192 tokens, E=512, LF=10, FAN=552.
// ---------------------------------------------------------------------------

#define PI_F 3.14159265358979323846f

static constexpr int   PP    = 1024;
static constexpr int   NT    = 8192;
static constexpr int   EE    = 512;
static constexpr int   FANC  = 552;
static constexpr int   KC    = 192;
static constexpr float BETA_F = 0.001f;
static constexpr float EPS_F  = 1e-5f;
static constexpr size_t NEs = (size_t)NT * EE;   // 4,194,304
static constexpr size_t PEs = (size_t)PP * EE;   //   524,288
static constexpr size_t SEs = (size_t)NT * PP;   // 8,388,608 (per-level P)

typedef __attribute__((ext_vector_type(8))) short short8v;  // 8 bf16
typedef __attribute__((ext_vector_type(4))) float f32x4;
typedef unsigned short u16;

__device__ __forceinline__ u16 f2bf(float x) {
  unsigned u = __float_as_uint(x);
  return (u16)((u + (((u >> 16) & 1u) + 0x7fffu)) >> 16);   // RNE
}
__device__ __forceinline__ float bf2f(u16 h) {
  return __uint_as_float(((unsigned)h) << 16);
}

__device__ __forceinline__ void gll16(const u16* g, u16* l) {
  __builtin_amdgcn_global_load_lds(
      (const __attribute__((address_space(1))) unsigned int*)g,
      (__attribute__((address_space(3))) unsigned int*)l, 16, 0, 0);
}

// swizzled LDS read: tile row-major [rows][64] bf16 (128B rows), chunk cb 0..7
__device__ __forceinline__ short8v ldsrd(const char* base, int row, int cb) {
  return *(const short8v*)(base + row*128 + (((cb ^ (row & 7)) << 4)));
}

// ---- 128x128 GEMM segment: C += A(128xK) * B(128xK)^T ---------------------
__device__ __forceinline__ void gemm128(
    const u16* __restrict__ Ab, int aStr,
    const u16* __restrict__ Bb, int bStr,
    int nsteps, char* As, char* Bs, int wbu, int lane, f32x4 (&acc)[4][4]) {
  int w = wbu >> 6, wr = w & 1, wc = w >> 1, lo = lane & 15, g = lane >> 4;
  for (int st = 0; st < nsteps; ++st) {
    int kk = st * 64;
    __syncthreads();
#pragma unroll
    for (int j = 0; j < 4; ++j) {
      int i = j*256 + wbu + lane;
      int r = i >> 3, c = (i & 7) ^ (r & 7);
      gll16(Ab + (size_t)r*aStr + kk + c*8, (u16*)(As + (j*256 + wbu)*16));
    }
#pragma unroll
    for (int j = 0; j < 4; ++j) {
      int i = j*256 + wbu + lane;
      int r = i >> 3, c = (i & 7) ^ (r & 7);
      gll16(Bb + (size_t)r*bStr + kk + c*8, (u16*)(Bs + (j*256 + wbu)*16));
    }
    __syncthreads();
#pragma unroll
    for (int h = 0; h < 2; ++h) {
      int cb = h*4 + g;
      short8v a[4], b[4];
#pragma unroll
      for (int m = 0; m < 4; ++m) a[m] = ldsrd(As, wr*64 + m*16 + lo, cb);
#pragma unroll
      for (int n = 0; n < 4; ++n) b[n] = ldsrd(Bs, wc*64 + n*16 + lo, cb);
#pragma unroll
      for (int m = 0; m < 4; ++m)
#pragma unroll
        for (int n = 0; n < 4; ++n)
          acc[m][n] = __builtin_amdgcn_mfma_f32_16x16x32_bf16(a[m], b[n], acc[m][n], 0, 0, 0);
    }
  }
}

// ---------------- positional-encoding table [P,40] --------------------------
__global__ void k_locb(float* __restrict__ locb) {
  int q = blockIdx.x * blockDim.x + threadIdx.x;
  if (q >= PP) return;
  int h = q >> 5, w = q & 31;
  float ph = 2.f * (float)h / 32.f - 1.f;
  float pw = 2.f * (float)w / 32.f - 1.f;
  float* d = locb + (size_t)q * 40;
#pragma unroll
  for (int j = 0; j < 10; ++j) {
    float f = (float)(1 << j) * PI_F;
    float ah = f * ph, aw = f * pw;
    d[2*j]     = sinf(ah); d[2*j+1]  = cosf(ah);
    d[20+2*j]  = sinf(aw); d[21+2*j] = cosf(aw);
  }
}

// ---- Wcomb[l][f][e], bcomb[l][e]: one pass over scattered weight layout ----
__global__ __launch_bounds__(256) void k_wcombT(
    const float* __restrict__ buw, const float* __restrict__ bub,
    const float* __restrict__ tdw, const float* __restrict__ tdb,
    const float* w2p, const float* w3p,
    float* __restrict__ Wcomb, float* __restrict__ bcomb) {
  int l = blockIdx.x, et = blockIdx.y, t = threadIdx.x;
  int e = et*64 + (t >> 2), fg = (t & 3)*10;
  float w2 = *w2p, w3 = *w3p;
  const float* bu = buw + ((size_t)l*EE + e)*FANC + EE;
  const float* td = tdw + ((size_t)l*EE + e)*FANC + EE;
#pragma unroll
  for (int j = 0; j < 10; ++j) {
    int f = fg + j;
    float v = 0.f;
    if (l > 0) v += w2 * bu[f];
    if (l < 4) v += w3 * td[f];
    Wcomb[((size_t)l*40 + f)*EE + e] = v;
  }
  if (fg == 0) {
    float bv = 0.f;
    if (l > 0) bv += w2 * bub[(size_t)l*EE + e];
    if (l < 4) bv += w3 * tdb[(size_t)l*EE + e];
    bcomb[(size_t)l*EE + e] = bv;
  }
}

// ---- Lcomb[l][q][e] via coalesced Wcomb, 16-q register blocking ------------
__global__ __launch_bounds__(256) void k_loccomb2(const float* __restrict__ locb,
    const float* __restrict__ Wcomb, const float* __restrict__ bcomb,
    u16* __restrict__ Lc) {
  int l = blockIdx.x, q0 = blockIdx.y * 16, t = threadIdx.x;
  __shared__ float lb[16][40];
  for (int i = t; i < 640; i += 256) lb[i/40][i%40] = locb[(size_t)(q0 + i/40)*40 + i%40];
  __syncthreads();
  float acc0[16] = {}, acc1[16] = {};
  const float* W = Wcomb + (size_t)l*40*EE;
#pragma unroll 8
  for (int f = 0; f < 40; ++f) {
    float wa = W[(size_t)f*EE + t];
    float wb = W[(size_t)f*EE + t + 256];
#pragma unroll
    for (int q = 0; q < 16; ++q) {
      acc0[q] += lb[q][f]*wa;
      acc1[q] += lb[q][f]*wb;
    }
  }
  float b0 = bcomb[(size_t)l*EE + t], b1 = bcomb[(size_t)l*EE + t + 256];
  u16* dst = Lc + (size_t)l*PEs + (size_t)q0*EE;
#pragma unroll
  for (int q = 0; q < 16; ++q) {
    dst[(size_t)q*EE + t]       = f2bf(acc0[q] + b0);
    dst[(size_t)q*EE + t + 256] = f2bf(acc1[q] + b1);
  }
}

// ---- bu/td weights -> bf16 with w2/w3 folded ------------------------------
__global__ __launch_bounds__(256) void k_wconv(const float* __restrict__ buw,
    const float* __restrict__ tdw, const float* w2p, const float* w3p,
    u16* __restrict__ Wbu, u16* __restrict__ Wtd) {
  int gid = blockIdx.x*256 + threadIdx.x;
  int which = blockIdx.y;
  int k8 = gid & 63;
  int row = gid >> 6;
  const float* src = (which ? tdw : buw) + (size_t)row*FANC + k8*8;
  float s = which ? *w3p : *w2p;
  u16* dst = (which ? Wtd : Wbu) + (size_t)row*EE + k8*8;
  short8v o;
#pragma unroll
  for (int j = 0; j < 8; ++j) o[j] = (short)f2bf(s*src[j]);
  *(short8v*)dst = o;
}

// ---- conv weights [512][192] f32 -> bf16 ----------------------------------
__global__ __launch_bounds__(256) void k_wcv(const float* __restrict__ cw,
                                             u16* __restrict__ Wc) {
  size_t i = ((size_t)blockIdx.x*256 + threadIdx.x)*8;
  short8v o;
#pragma unroll
  for (int j = 0; j < 8; ++j) o[j] = (short)f2bf(cw[i + j]);
  *(short8v*)(Wc + i) = o;
}

// ---- im2col: x [8][3][256][256] f32 -> Apat [8192][192] bf16 ---------------
__global__ __launch_bounds__(256) void k_im2col(const float* __restrict__ x,
                                                u16* __restrict__ Apat) {
  int t = threadIdx.x;
  int R = blockIdx.x*8 + (t >> 5);
  int wtok = t & 31;
  int b = R / 768, rem = R - b*768, c = rem >> 8, h8 = rem & 255;
  int h = h8 >> 3, kh = h8 & 7;
  const float* src = x + (size_t)R*256 + wtok*8;
  float4 v0 = *(const float4*)src, v1 = *(const float4*)(src + 4);
  short8v o;
  o[0]=(short)f2bf(v0.x); o[1]=(short)f2bf(v0.y); o[2]=(short)f2bf(v0.z); o[3]=(short)f2bf(v0.w);
  o[4]=(short)f2bf(v1.x); o[5]=(short)f2bf(v1.y); o[6]=(short)f2bf(v1.z); o[7]=(short)f2bf(v1.w);
  int n = b*1024 + h*32 + wtok;
  *(short8v*)(Apat + (size_t)n*KC + c*64 + kh*8) = o;
}

// ---- conv GEMM: BpreA[0][n][e] = Apat @ Wc^T + cb, + statsA ----------------
__global__ __launch_bounds__(256) void k_cgemm(const u16* __restrict__ Apat,
    const u16* __restrict__ Wc, const float* __restrict__ cb,
    u16* __restrict__ Obf, float* __restrict__ statsA) {
  __shared__ char As[16384];
  __shared__ char Bs[16384];
  int tid = threadIdx.x, lane = tid & 63;
  int wbu = __builtin_amdgcn_readfirstlane(tid & ~63);
  int w = wbu >> 6, wr = w & 1, wc = w >> 1, lo = lane & 15, g = lane >> 4;
  int n0 = blockIdx.x*128, e0 = blockIdx.y*128;
  f32x4 acc[4][4] = {};
  gemm128(Apat + (size_t)n0*KC, KC, Wc + (size_t)e0*KC, KC, 3, As, Bs, wbu, lane, acc);
  float stS[4] = {}, stQ[4] = {};
#pragma unroll
  for (int m = 0; m < 4; ++m)
#pragma unroll
    for (int n = 0; n < 4; ++n) {
      int e = e0 + wc*64 + n*16 + lo;
      float bias = cb[e];
#pragma unroll
      for (int r = 0; r < 4; ++r) {
        int row = n0 + wr*64 + m*16 + g*4 + r;
        float v = acc[m][n][r] + bias;
        Obf[(size_t)row*EE + e] = f2bf(v);
        stS[n] += v; stQ[n] += v*v;
      }
    }
#pragma unroll
  for (int n = 0; n < 4; ++n) {
    float s = stS[n], q2 = stQ[n];
    s  += __shfl_xor(s, 16);  s  += __shfl_xor(s, 32);
    q2 += __shfl_xor(q2, 16); q2 += __shfl_xor(q2, 32);
    if (g == 0) {
      int e = e0 + wc*64 + n*16 + lo;
      atomicAdd(&statsA[e], s);
      atomicAdd(&statsA[EE + e], q2);
    }
  }
}

// ---- BN apply, all levels: z = l*8+b ---------------------------------------
__global__ __launch_bounds__(256) void k_bnx(const u16* __restrict__ BpreCur,
    const float* __restrict__ statsBase, const float* __restrict__ gam,
    const float* __restrict__ bta, u16* __restrict__ BpostAll,
    u16* __restrict__ XbfTAll) {
  __shared__ u16 tile[32][34];
  __shared__ float ssl[2][32];
  int l = blockIdx.z >> 3, b = blockIdx.z & 7;
  int p0 = blockIdx.x * 32, e0 = blockIdx.y * 32;
  int tr = threadIdx.x >> 5, tc = threadIdx.x & 31;
  const float* stats = statsBase + (size_t)l*1024;
  if (threadIdx.x < 32) {
    int c = e0 + threadIdx.x;
    float mean = stats[c] * (1.f/8192.f);
    float var  = stats[EE + c] * (1.f/8192.f) - mean*mean;
    var = fmaxf(var, 0.f);
    float sc = gam[(size_t)l*EE + c] * rsqrtf(var + EPS_F);
    ssl[0][threadIdx.x] = sc;
    ssl[1][threadIdx.x] = bta[(size_t)l*EE + c] - mean*sc;
  }
  __syncthreads();
  float sc = ssl[0][tc], sh = ssl[1][tc];
  const u16* Xh = BpreCur + (size_t)l*NEs;
  u16* Bpost = BpostAll + (size_t)l*NEs;
  u16* XbfT  = XbfTAll + (size_t)l*NEs;
#pragma unroll
  for (int i = 0; i < 4; ++i) {
    int p = tr + 8*i;
    size_t idx = (size_t)(b*PP + p0 + p)*EE + e0 + tc;
    u16 us = f2bf(bf2f(Xh[idx])*sc + sh);
    Bpost[idx] = us;
    tile[p][tc] = us;
  }
  __syncthreads();
#pragma unroll
  for (int i = 0; i < 4; ++i) {
    int e = tr + 8*i;
    XbfT[(size_t)(b*EE + e0 + e)*PP + p0 + tc] = tile[tc][e];
  }
}

// ---- GEMM1 all levels: P[l] = exp(beta*X X^T), denom atomics ---------------
// 1D grid 2560 = 8 XCD chunks of 320; (l,b) slowest so each XCD keeps its
// 2MB X operand L2-resident across the 64 blocks of each (l,b).
__global__ __launch_bounds__(256) void k_gemm1(const u16* __restrict__ BpostAll,
    u16* __restrict__ PAll, float* __restrict__ denomCyc) {
  __shared__ char As[16384];
  __shared__ char Bs[16384];
  int tid = threadIdx.x, lane = tid & 63;
  int wbu = __builtin_amdgcn_readfirstlane(tid & ~63);
  int w = wbu >> 6, wr = w & 1, wc = w >> 1, lo = lane & 15, g = lane >> 4;
  int bid = blockIdx.x;
  int logical = (bid & 7) * 320 + (bid >> 3);   // XCD-chunked, bijective
  int z = logical >> 6;                          // (l,b) 0..39
  int rem = logical & 63;
  int q0 = (rem >> 3) * 128;                     // A panel shared by 8 adjacent
  int k0 = (rem & 7) * 128;
  int l = z >> 3, b = z & 7;
  const u16* Xb = BpostAll + (size_t)l*NEs;
  u16* P = PAll + (size_t)l*SEs;
  float* denom = denomCyc + (size_t)l*1024;
  f32x4 acc[4][4] = {};
  gemm128(Xb + ((size_t)(b*PP + q0))*EE, EE, Xb + ((size_t)(b*PP + k0))*EE, EE,
          8, As, Bs, wbu, lane, acc);
  float rs[4][4] = {};
#pragma unroll
  for (int m = 0; m < 4; ++m)
#pragma unroll
    for (int n = 0; n < 4; ++n)
#pragma unroll
      for (int r = 0; r < 4; ++r) {
        float ex = __expf(BETA_F * acc[m][n][r]);
        rs[m][r] += ex;
        int q = q0 + wr*64 + m*16 + g*4 + r;
        int k = k0 + wc*64 + n*16 + lo;
        P[((size_t)(b*PP) + q)*PP + k] = f2bf(ex);
      }
#pragma unroll
  for (int m = 0; m < 4; ++m)
#pragma unroll
    for (int r = 0; r < 4; ++r) {
      float v = rs[m][r];
      v += __shfl_xor(v, 1); v += __shfl_xor(v, 2);
      v += __shfl_xor(v, 4); v += __shfl_xor(v, 8);
      if (lo == 0) atomicAdd(&denom[q0 + wr*64 + m*16 + g*4 + r], v);
    }
}

// ---- mega all levels: O[l] = PV*w4/denom + bu + td + w1*Xbn + Lcomb --------
// 1D grid 1280 = 8 XCD chunks of 160; e0 fastest (4 blocks share a 256KB P
// panel back-to-back on one XCD), n0 next (weight panels reused every 4
// blocks; V panels hot per batch-span), l slowest.
template<int ACCST>
__global__ __launch_bounds__(256) void k_mega(
    const u16* __restrict__ BpostAll, const u16* __restrict__ BpreCur,
    const u16* __restrict__ PAll, const u16* __restrict__ XbfTAll,
    const u16* __restrict__ WbuAll, const u16* __restrict__ WtdAll,
    const u16* __restrict__ LcAll,
    const float* __restrict__ w1p, const float* __restrict__ w4p,
    const float* __restrict__ denomCyc, float* __restrict__ statsB,
    u16* __restrict__ BpreNext) {
  __shared__ char As[16384];
  __shared__ char Bs[16384];
  int tid = threadIdx.x, lane = tid & 63;
  int wbu = __builtin_amdgcn_readfirstlane(tid & ~63);
  int w = wbu >> 6, wr = w & 1, wc = w >> 1, lo = lane & 15, g = lane >> 4;
  int bid = blockIdx.x;
  int logical = (bid & 7) * 160 + (bid >> 3);   // XCD-chunked, bijective
  int l = logical >> 8;                          // /256, 0..4
  int rem = logical & 255;
  int n0 = (rem >> 2) * 128;
  int e0 = (rem & 3) * 128;
  int b = n0 >> 10;
  const float* denom = denomCyc + (size_t)l*1024;
  f32x4 acc[4][4] = {};
  // PV first, then scale by w4/denom in registers
  gemm128(PAll + (size_t)l*SEs + (size_t)n0*PP, PP,
          XbfTAll + (size_t)l*NEs + (size_t)b*EE*PP + (size_t)e0*PP, PP, 16,
          As, Bs, wbu, lane, acc);
  float w4 = *w4p;
#pragma unroll
  for (int m = 0; m < 4; ++m)
#pragma unroll
    for (int r = 0; r < 4; ++r) {
      int q = (n0 + wr*64 + m*16 + g*4 + r) & 1023;
      float s = w4 / denom[q];
#pragma unroll
      for (int n = 0; n < 4; ++n) acc[m][n][r] *= s;
    }
  if (l > 0)
    gemm128(BpostAll + (size_t)(l-1)*NEs + (size_t)n0*EE, EE,
            WbuAll + (size_t)l*EE*EE + (size_t)e0*EE, EE, 8, As, Bs, wbu, lane, acc);
  if (l < 4)
    gemm128(BpreCur + (size_t)(l+1)*NEs + (size_t)n0*EE, EE,
            WtdAll + (size_t)l*EE*EE + (size_t)e0*EE, EE, 8, As, Bs, wbu, lane, acc);
  float w1 = *w1p;
  const u16* Xh = BpostAll + (size_t)l*NEs;
  const u16* Lc = LcAll + (size_t)l*PEs;
  u16* Obf = BpreNext + (size_t)l*NEs;
  float stS[4] = {}, stQ[4] = {};
#pragma unroll
  for (int m = 0; m < 4; ++m)
#pragma unroll
    for (int n = 0; n < 4; ++n)
#pragma unroll
      for (int r = 0; r < 4; ++r) {
        int nn = n0 + wr*64 + m*16 + g*4 + r;
        int e = e0 + wc*64 + n*16 + lo;
        size_t idx = (size_t)nn*EE + e;
        float v = acc[m][n][r] + w1*bf2f(Xh[idx]) + bf2f(Lc[(size_t)(nn & 1023)*EE + e]);
        Obf[idx] = f2bf(v);
        if (ACCST) { stS[n] += v; stQ[n] += v*v; }
      }
  if (ACCST) {
#pragma unroll
    for (int n = 0; n < 4; ++n) {
      float s = stS[n], q2 = stQ[n];
      s  += __shfl_xor(s, 16);  s  += __shfl_xor(s, 32);
      q2 += __shfl_xor(q2, 16); q2 += __shfl_xor(q2, 32);
      if (g == 0) {
        int e = e0 + wc*64 + n*16 + lo;
        atomicAdd(&statsB[(size_t)l*1024 + e], s);
        atomicAdd(&statsB[(size_t)l*1024 + EE + e], q2);
      }
    }
  }
}

// ---- final transpose: Bpre bf16 [l][b][hw][e] -> out f32 [b][e][hw][5] -----
__global__ __launch_bounds__(256) void k_transpose_bf(const u16* __restrict__ Bpre,
                                                      float* __restrict__ out) {
  __shared__ u16 tile[5][32][34];
  int t = threadIdx.x;
  int hw0 = blockIdx.x * 32, e0 = blockIdx.y * 32, b = blockIdx.z;
  int tr = t >> 5, tc = t & 31;
#pragma unroll
  for (int l = 0; l < 5; ++l) {
    const u16* src = Bpre + (size_t)l*NEs + ((size_t)(b*PP + hw0))*EE + e0;
    for (int p = 0; p < 4; ++p)
      tile[l][tr + 8*p][tc] = src[(size_t)(tr + 8*p)*EE + tc];
  }
  __syncthreads();
  for (int p = 0; p < 4; ++p) {
    int e = tr + 8*p;
    float* dst = out + (((size_t)(b*EE + e0 + e))*PP + (size_t)(hw0 + tc))*5;
#pragma unroll
    for (int l = 0; l < 5; ++l) dst[l] = bf2f(tile[l][tc][e]);
  }
}

// ---------------------------------------------------------------------------
extern "C" void kernel_launch(void* const* d_in, const int* in_sizes, int n_in,
                              void* d_out, int out_size, void* d_ws, size_t ws_size,
                              hipStream_t stream) {
  const float* x     = (const float*)d_in[0];
  const float* convw = (const float*)d_in[1];
  const float* convb = (const float*)d_in[2];
  const float* bu_w  = (const float*)d_in[3];
  const float* bu_b  = (const float*)d_in[4];
  const float* td_w  = (const float*)d_in[5];
  const float* td_b  = (const float*)d_in[6];
  const float* bn_g  = (const float*)d_in[7];
  const float* bn_b  = (const float*)d_in[8];
  const float* w1 = (const float*)d_in[9];
  const float* w2 = (const float*)d_in[10];
  const float* w3 = (const float*)d_in[11];
  const float* w4 = (const float*)d_in[12];
  float* out = (float*)d_out;

  // ws layout (u16 units unless noted); total ~266 MB
  u16* BpreA  = (u16*)d_ws;                    // 5*NE  cycle-0 in / cycle-1 out
  u16* BpreB  = BpreA + 5*NEs;                 // 5*NE  cycle-0 out / cycle-1 in
  u16* BpostA = BpreB + 5*NEs;                 // 5*NE  post-BN (all levels)
  u16* XbfTA  = BpostA + 5*NEs;                // 5*NE  transposed post-BN
  u16* PAll   = XbfTA + 5*NEs;                 // 5*SEs P matrices
  u16* Lcomb  = PAll + 5*SEs;                  // 5*PE
  u16* Wbu_s  = Lcomb + 5*PEs;                 // 5*512*512
  u16* Wtd_s  = Wbu_s + (size_t)5*EE*EE;       // 5*512*512
  u16* Apat   = Wtd_s + (size_t)5*EE*EE;       // 8192*192
  u16* Wcv    = Apat + (size_t)NT*KC;          // 512*192
  float* locb   = (float*)(Wcv + (size_t)EE*KC);   // 40960 f32
  float* Wcomb  = locb + 40960;                // 5*40*512
  float* bcomb  = Wcomb + 102400;              // 2560
  float* statsA = bcomb + 2560;                // 5*1024
  float* statsB = statsA + 5*1024;             // 5*1024
  float* denomAll = statsB + 5*1024;           // 10*1024

  // ---- setup ----
  k_locb<<<4, 256, 0, stream>>>(locb);
  k_wcombT<<<dim3(5, 8), 256, 0, stream>>>(bu_w, bu_b, td_w, td_b, w2, w3, Wcomb, bcomb);
  k_loccomb2<<<dim3(5, 64), 256, 0, stream>>>(locb, Wcomb, bcomb, Lcomb);
  k_wconv<<<dim3(640, 2), 256, 0, stream>>>(bu_w, td_w, w2, w3, Wbu_s, Wtd_s);
  k_wcv<<<48, 256, 0, stream>>>(convw, Wcv);
  k_im2col<<<768, 256, 0, stream>>>(x, Apat);
  hipMemsetAsync(BpreA + NEs, 0, 4*NEs*sizeof(u16), stream);   // levels 1..4 zero
  hipMemsetAsync(statsA, 0, (5*1024 + 5*1024 + 10*1024)*sizeof(float), stream);
  k_cgemm<<<dim3(64, 4), 256, 0, stream>>>(Apat, Wcv, convb, BpreA, statsA);

  for (int cyc = 0; cyc < 2; ++cyc) {
    u16* BpreCur  = (cyc == 0) ? BpreA : BpreB;
    u16* BpreNext = (cyc == 0) ? BpreB : BpreA;
    const float* statsSel = (cyc == 0) ? statsA : statsB;
    float* denomCyc = denomAll + (size_t)cyc*5*1024;
    k_bnx<<<dim3(32,16,40), 256, 0, stream>>>(BpreCur, statsSel, bn_g, bn_b,
                                              BpostA, XbfTA);
    k_gemm1<<<2560, 256, 0, stream>>>(BpostA, PAll, denomCyc);
    if (cyc == 0)
      k_mega<1><<<1280, 256, 0, stream>>>(BpostA, BpreCur, PAll, XbfTA,
          Wbu_s, Wtd_s, Lcomb, w1, w4, denomCyc, statsB, BpreNext);
    else
      k_mega<0><<<1280, 256, 0, stream>>>(BpostA, BpreCur, PAll, XbfTA,
          Wbu_s, Wtd_s, Lcomb, w1, w4, denomCyc, nullptr, BpreNext);
  }
  k_transpose_bf<<<dim3(32,16,8), 256, 0, stream>>>(BpreA, out);
}

// Round 8
// 462.092 us; speedup vs baseline: 24.2416x; 1.0473x over previous
//
#include <hip/hip_runtime.h>

// ---------------------------------------------------------------------------
// GLOM forward. Round 8: symmetric-half gemm1 (exploit P = P^T, ~44% fewer
// FLOPs + col-sum harvest), step-weighted XCD chunks for k_mega balance.
// B=8, H=W=32, P=1024, N=8192 tokens, E=512, LF=10, FAN=552.
// ---------------------------------------------------------------------------

#define PI_F 3.14159265358979323846f

static constexpr int   PP    = 1024;
static constexpr int   NT    = 8192;
static constexpr int   EE    = 512;
static constexpr int   FANC  = 552;
static constexpr int   KC    = 192;
static constexpr float BETA_F = 0.001f;
static constexpr float EPS_F  = 1e-5f;
static constexpr size_t NEs = (size_t)NT * EE;   // 4,194,304
static constexpr size_t PEs = (size_t)PP * EE;   //   524,288
static constexpr size_t SEs = (size_t)NT * PP;   // 8,388,608 (per-level P)

typedef __attribute__((ext_vector_type(8))) short short8v;  // 8 bf16
typedef __attribute__((ext_vector_type(4))) float f32x4;
typedef unsigned short u16;

__device__ __forceinline__ u16 f2bf(float x) {
  unsigned u = __float_as_uint(x);
  return (u16)((u + (((u >> 16) & 1u) + 0x7fffu)) >> 16);   // RNE
}
__device__ __forceinline__ float bf2f(u16 h) {
  return __uint_as_float(((unsigned)h) << 16);
}

__device__ __forceinline__ void gll16(const u16* g, u16* l) {
  __builtin_amdgcn_global_load_lds(
      (const __attribute__((address_space(1))) unsigned int*)g,
      (__attribute__((address_space(3))) unsigned int*)l, 16, 0, 0);
}

// swizzled LDS read: tile row-major [rows][64] bf16 (128B rows), chunk cb 0..7
__device__ __forceinline__ short8v ldsrd(const char* base, int row, int cb) {
  return *(const short8v*)(base + row*128 + (((cb ^ (row & 7)) << 4)));
}

// ---- 128x128 GEMM segment: C += A(128xK) * B(128xK)^T ---------------------
__device__ __forceinline__ void gemm128(
    const u16* __restrict__ Ab, int aStr,
    const u16* __restrict__ Bb, int bStr,
    int nsteps, char* As, char* Bs, int wbu, int lane, f32x4 (&acc)[4][4]) {
  int w = wbu >> 6, wr = w & 1, wc = w >> 1, lo = lane & 15, g = lane >> 4;
  for (int st = 0; st < nsteps; ++st) {
    int kk = st * 64;
    __syncthreads();
#pragma unroll
    for (int j = 0; j < 4; ++j) {
      int i = j*256 + wbu + lane;
      int r = i >> 3, c = (i & 7) ^ (r & 7);
      gll16(Ab + (size_t)r*aStr + kk + c*8, (u16*)(As + (j*256 + wbu)*16));
    }
#pragma unroll
    for (int j = 0; j < 4; ++j) {
      int i = j*256 + wbu + lane;
      int r = i >> 3, c = (i & 7) ^ (r & 7);
      gll16(Bb + (size_t)r*bStr + kk + c*8, (u16*)(Bs + (j*256 + wbu)*16));
    }
    __syncthreads();
#pragma unroll
    for (int h = 0; h < 2; ++h) {
      int cb = h*4 + g;
      short8v a[4], b[4];
#pragma unroll
      for (int m = 0; m < 4; ++m) a[m] = ldsrd(As, wr*64 + m*16 + lo, cb);
#pragma unroll
      for (int n = 0; n < 4; ++n) b[n] = ldsrd(Bs, wc*64 + n*16 + lo, cb);
#pragma unroll
      for (int m = 0; m < 4; ++m)
#pragma unroll
        for (int n = 0; n < 4; ++n)
          acc[m][n] = __builtin_amdgcn_mfma_f32_16x16x32_bf16(a[m], b[n], acc[m][n], 0, 0, 0);
    }
  }
}

// ---------------- positional-encoding table [P,40] --------------------------
__global__ void k_locb(float* __restrict__ locb) {
  int q = blockIdx.x * blockDim.x + threadIdx.x;
  if (q >= PP) return;
  int h = q >> 5, w = q & 31;
  float ph = 2.f * (float)h / 32.f - 1.f;
  float pw = 2.f * (float)w / 32.f - 1.f;
  float* d = locb + (size_t)q * 40;
#pragma unroll
  for (int j = 0; j < 10; ++j) {
    float f = (float)(1 << j) * PI_F;
    float ah = f * ph, aw = f * pw;
    d[2*j]     = sinf(ah); d[2*j+1]  = cosf(ah);
    d[20+2*j]  = sinf(aw); d[21+2*j] = cosf(aw);
  }
}

// ---- Wcomb[l][f][e], bcomb[l][e]: one pass over scattered weight layout ----
__global__ __launch_bounds__(256) void k_wcombT(
    const float* __restrict__ buw, const float* __restrict__ bub,
    const float* __restrict__ tdw, const float* __restrict__ tdb,
    const float* w2p, const float* w3p,
    float* __restrict__ Wcomb, float* __restrict__ bcomb) {
  int l = blockIdx.x, et = blockIdx.y, t = threadIdx.x;
  int e = et*64 + (t >> 2), fg = (t & 3)*10;
  float w2 = *w2p, w3 = *w3p;
  const float* bu = buw + ((size_t)l*EE + e)*FANC + EE;
  const float* td = tdw + ((size_t)l*EE + e)*FANC + EE;
#pragma unroll
  for (int j = 0; j < 10; ++j) {
    int f = fg + j;
    float v = 0.f;
    if (l > 0) v += w2 * bu[f];
    if (l < 4) v += w3 * td[f];
    Wcomb[((size_t)l*40 + f)*EE + e] = v;
  }
  if (fg == 0) {
    float bv = 0.f;
    if (l > 0) bv += w2 * bub[(size_t)l*EE + e];
    if (l < 4) bv += w3 * tdb[(size_t)l*EE + e];
    bcomb[(size_t)l*EE + e] = bv;
  }
}

// ---- Lcomb[l][q][e] via coalesced Wcomb, 16-q register blocking ------------
__global__ __launch_bounds__(256) void k_loccomb2(const float* __restrict__ locb,
    const float* __restrict__ Wcomb, const float* __restrict__ bcomb,
    u16* __restrict__ Lc) {
  int l = blockIdx.x, q0 = blockIdx.y * 16, t = threadIdx.x;
  __shared__ float lb[16][40];
  for (int i = t; i < 640; i += 256) lb[i/40][i%40] = locb[(size_t)(q0 + i/40)*40 + i%40];
  __syncthreads();
  float acc0[16] = {}, acc1[16] = {};
  const float* W = Wcomb + (size_t)l*40*EE;
#pragma unroll 8
  for (int f = 0; f < 40; ++f) {
    float wa = W[(size_t)f*EE + t];
    float wb = W[(size_t)f*EE + t + 256];
#pragma unroll
    for (int q = 0; q < 16; ++q) {
      acc0[q] += lb[q][f]*wa;
      acc1[q] += lb[q][f]*wb;
    }
  }
  float b0 = bcomb[(size_t)l*EE + t], b1 = bcomb[(size_t)l*EE + t + 256];
  u16* dst = Lc + (size_t)l*PEs + (size_t)q0*EE;
#pragma unroll
  for (int q = 0; q < 16; ++q) {
    dst[(size_t)q*EE + t]       = f2bf(acc0[q] + b0);
    dst[(size_t)q*EE + t + 256] = f2bf(acc1[q] + b1);
  }
}

// ---- bu/td weights -> bf16 with w2/w3 folded ------------------------------
__global__ __launch_bounds__(256) void k_wconv(const float* __restrict__ buw,
    const float* __restrict__ tdw, const float* w2p, const float* w3p,
    u16* __restrict__ Wbu, u16* __restrict__ Wtd) {
  int gid = blockIdx.x*256 + threadIdx.x;
  int which = blockIdx.y;
  int k8 = gid & 63;
  int row = gid >> 6;
  const float* src = (which ? tdw : buw) + (size_t)row*FANC + k8*8;
  float s = which ? *w3p : *w2p;
  u16* dst = (which ? Wtd : Wbu) + (size_t)row*EE + k8*8;
  short8v o;
#pragma unroll
  for (int j = 0; j < 8; ++j) o[j] = (short)f2bf(s*src[j]);
  *(short8v*)dst = o;
}

// ---- conv weights [512][192] f32 -> bf16 ----------------------------------
__global__ __launch_bounds__(256) void k_wcv(const float* __restrict__ cw,
                                             u16* __restrict__ Wc) {
  size_t i = ((size_t)blockIdx.x*256 + threadIdx.x)*8;
  short8v o;
#pragma unroll
  for (int j = 0; j < 8; ++j) o[j] = (short)f2bf(cw[i + j]);
  *(short8v*)(Wc + i) = o;
}

// ---- im2col: x [8][3][256][256] f32 -> Apat [8192][192] bf16 ---------------
__global__ __launch_bounds__(256) void k_im2col(const float* __restrict__ x,
                                                u16* __restrict__ Apat) {
  int t = threadIdx.x;
  int R = blockIdx.x*8 + (t >> 5);
  int wtok = t & 31;
  int b = R / 768, rem = R - b*768, c = rem >> 8, h8 = rem & 255;
  int h = h8 >> 3, kh = h8 & 7;
  const float* src = x + (size_t)R*256 + wtok*8;
  float4 v0 = *(const float4*)src, v1 = *(const float4*)(src + 4);
  short8v o;
  o[0]=(short)f2bf(v0.x); o[1]=(short)f2bf(v0.y); o[2]=(short)f2bf(v0.z); o[3]=(short)f2bf(v0.w);
  o[4]=(short)f2bf(v1.x); o[5]=(short)f2bf(v1.y); o[6]=(short)f2bf(v1.z); o[7]=(short)f2bf(v1.w);
  int n = b*1024 + h*32 + wtok;
  *(short8v*)(Apat + (size_t)n*KC + c*64 + kh*8) = o;
}

// ---- conv GEMM: BpreA[0][n][e] = Apat @ Wc^T + cb, + statsA ----------------
__global__ __launch_bounds__(256) void k_cgemm(const u16* __restrict__ Apat,
    const u16* __restrict__ Wc, const float* __restrict__ cb,
    u16* __restrict__ Obf, float* __restrict__ statsA) {
  __shared__ char As[16384];
  __shared__ char Bs[16384];
  int tid = threadIdx.x, lane = tid & 63;
  int wbu = __builtin_amdgcn_readfirstlane(tid & ~63);
  int w = wbu >> 6, wr = w & 1, wc = w >> 1, lo = lane & 15, g = lane >> 4;
  int n0 = blockIdx.x*128, e0 = blockIdx.y*128;
  f32x4 acc[4][4] = {};
  gemm128(Apat + (size_t)n0*KC, KC, Wc + (size_t)e0*KC, KC, 3, As, Bs, wbu, lane, acc);
  float stS[4] = {}, stQ[4] = {};
#pragma unroll
  for (int m = 0; m < 4; ++m)
#pragma unroll
    for (int n = 0; n < 4; ++n) {
      int e = e0 + wc*64 + n*16 + lo;
      float bias = cb[e];
#pragma unroll
      for (int r = 0; r < 4; ++r) {
        int row = n0 + wr*64 + m*16 + g*4 + r;
        float v = acc[m][n][r] + bias;
        Obf[(size_t)row*EE + e] = f2bf(v);
        stS[n] += v; stQ[n] += v*v;
      }
    }
#pragma unroll
  for (int n = 0; n < 4; ++n) {
    float s = stS[n], q2 = stQ[n];
    s  += __shfl_xor(s, 16);  s  += __shfl_xor(s, 32);
    q2 += __shfl_xor(q2, 16); q2 += __shfl_xor(q2, 32);
    if (g == 0) {
      int e = e0 + wc*64 + n*16 + lo;
      atomicAdd(&statsA[e], s);
      atomicAdd(&statsA[EE + e], q2);
    }
  }
}

// ---- BN apply, all levels: z = l*8+b ---------------------------------------
__global__ __launch_bounds__(256) void k_bnx(const u16* __restrict__ BpreCur,
    const float* __restrict__ statsBase, const float* __restrict__ gam,
    const float* __restrict__ bta, u16* __restrict__ BpostAll,
    u16* __restrict__ XbfTAll) {
  __shared__ u16 tile[32][34];
  __shared__ float ssl[2][32];
  int l = blockIdx.z >> 3, b = blockIdx.z & 7;
  int p0 = blockIdx.x * 32, e0 = blockIdx.y * 32;
  int tr = threadIdx.x >> 5, tc = threadIdx.x & 31;
  const float* stats = statsBase + (size_t)l*1024;
  if (threadIdx.x < 32) {
    int c = e0 + threadIdx.x;
    float mean = stats[c] * (1.f/8192.f);
    float var  = stats[EE + c] * (1.f/8192.f) - mean*mean;
    var = fmaxf(var, 0.f);
    float sc = gam[(size_t)l*EE + c] * rsqrtf(var + EPS_F);
    ssl[0][threadIdx.x] = sc;
    ssl[1][threadIdx.x] = bta[(size_t)l*EE + c] - mean*sc;
  }
  __syncthreads();
  float sc = ssl[0][tc], sh = ssl[1][tc];
  const u16* Xh = BpreCur + (size_t)l*NEs;
  u16* Bpost = BpostAll + (size_t)l*NEs;
  u16* XbfT  = XbfTAll + (size_t)l*NEs;
#pragma unroll
  for (int i = 0; i < 4; ++i) {
    int p = tr + 8*i;
    size_t idx = (size_t)(b*PP + p0 + p)*EE + e0 + tc;
    u16 us = f2bf(bf2f(Xh[idx])*sc + sh);
    Bpost[idx] = us;
    tile[p][tc] = us;
  }
  __syncthreads();
#pragma unroll
  for (int i = 0; i < 4; ++i) {
    int e = tr + 8*i;
    XbfT[(size_t)(b*EE + e0 + e)*PP + p0 + tc] = tile[tc][e];
  }
}

// ---- GEMM1 symmetric-half: P[l] = exp(beta*X X^T), both halves written -----
// Per (l,b): 36 upper-triangle tiles (qt<=kt). Off-diagonal tiles are written
// directly AND transposed (via padded LDS tile); row-sums from rows, the
// mirror tile's row-sums from column-sums. 1440 blocks = 8 XCD chunks of 180.
__global__ __launch_bounds__(256) void k_gemm1(const u16* __restrict__ BpostAll,
    u16* __restrict__ PAll, float* __restrict__ denomCyc) {
  __shared__ char LDS[33280];          // gemm: As=LDS, Bs=LDS+16K; ex-tile: all
  char* As = LDS;
  char* Bs = LDS + 16384;
  int tid = threadIdx.x, lane = tid & 63;
  int wbu = __builtin_amdgcn_readfirstlane(tid & ~63);
  int w = wbu >> 6, wr = w & 1, wc = w >> 1, lo = lane & 15, g = lane >> 4;
  int bid = blockIdx.x;
  int logical = (bid & 7) * 180 + (bid >> 3);   // XCD-chunked, bijective
  int z = logical / 36;                          // (l,b) 0..39
  int t36 = logical - z*36;
  int qt = 0, remt = t36;
  while (remt >= 8 - qt) { remt -= 8 - qt; ++qt; }
  int kt = qt + remt;                            // qt <= kt
  int l = z >> 3, b = z & 7;
  int q0 = qt*128, k0 = kt*128;
  const u16* Xb = BpostAll + (size_t)l*NEs;
  u16* P = PAll + (size_t)l*SEs;
  float* denom = denomCyc + (size_t)l*1024;
  bool offdiag = (qt != kt);

  f32x4 acc[4][4] = {};
  gemm128(Xb + ((size_t)(b*PP + q0))*EE, EE, Xb + ((size_t)(b*PP + k0))*EE, EE,
          8, As, Bs, wbu, lane, acc);

  if (offdiag) __syncthreads();        // drain gemm LDS reads before reuse
  u16* exs = (u16*)LDS;                // [128][130] padded bf16 tile
  float rs[4][4] = {};                 // row sums  [m][r]
  float cs[4]    = {0.f, 0.f, 0.f, 0.f};  // col sums [n]
#pragma unroll
  for (int m = 0; m < 4; ++m)
#pragma unroll
    for (int n = 0; n < 4; ++n)
#pragma unroll
      for (int r = 0; r < 4; ++r) {
        float ex = __expf(BETA_F * acc[m][n][r]);
        rs[m][r] += ex;
        cs[n] += ex;
        int qr = wr*64 + m*16 + g*4 + r;       // local row
        int kc = wc*64 + n*16 + lo;            // local col
        u16 h = f2bf(ex);
        P[((size_t)(b*PP) + q0 + qr)*PP + k0 + kc] = h;
        if (offdiag) exs[qr*130 + kc] = h;
      }

  if (offdiag) {
    __syncthreads();
    // transposed write: P[k0+krow][q0+qcol] = ex(qcol,krow), coalesced u32
    u16* Pt = P + ((size_t)(b*PP + k0))*PP + q0;
    int kr = tid >> 5, qp = tid & 31;
    for (int kk = 0; kk < 16; ++kk) {
      int krow = kk*8 + kr;
#pragma unroll
      for (int qh = 0; qh < 2; ++qh) {
        int qc = qh*64 + qp*2;
        unsigned v0 = exs[qc*130 + krow];
        unsigned v1 = exs[(qc+1)*130 + krow];
        *(unsigned*)(Pt + (size_t)krow*PP + qc) = v0 | (v1 << 16);
      }
    }
    // mirror-row sums (= this tile's column sums)
#pragma unroll
    for (int n = 0; n < 4; ++n) {
      float v = cs[n];
      v += __shfl_xor(v, 16); v += __shfl_xor(v, 32);
      if (g == 0) atomicAdd(&denom[k0 + wc*64 + n*16 + lo], v);
    }
  }
  // direct row sums
#pragma unroll
  for (int m = 0; m < 4; ++m)
#pragma unroll
    for (int r = 0; r < 4; ++r) {
      float v = rs[m][r];
      v += __shfl_xor(v, 1); v += __shfl_xor(v, 2);
      v += __shfl_xor(v, 4); v += __shfl_xor(v, 8);
      if (lo == 0) atomicAdd(&denom[q0 + wr*64 + m*16 + g*4 + r], v);
    }
}

// ---- mega all levels: O[l] = PV*w4/denom + bu + td + w1*Xbn + Lcomb --------
// Grid 1536 = 8 XCD chunks of 192 slots; step-weighted chunk sizes
// {192,160,144,144,144,144,160,192} equalize K-steps (4608/XCD); excess
// slots exit early. Within a chunk: e0 fastest (P-panel adjacency), n0 next.
template<int ACCST>
__global__ __launch_bounds__(256) void k_mega(
    const u16* __restrict__ BpostAll, const u16* __restrict__ BpreCur,
    const u16* __restrict__ PAll, const u16* __restrict__ XbfTAll,
    const u16* __restrict__ WbuAll, const u16* __restrict__ WtdAll,
    const u16* __restrict__ LcAll,
    const float* __restrict__ w1p, const float* __restrict__ w4p,
    const float* __restrict__ denomCyc, float* __restrict__ statsB,
    u16* __restrict__ BpreNext) {
  int bid = blockIdx.x;
  int xcd = bid & 7, idx = bid >> 3;             // idx 0..191
  int e0a = (xcd == 0) | (xcd == 7);
  int e1a = (xcd == 1) | (xcd == 6);
  int sz  = 144 + 48*e0a + 16*e1a;
  if (idx >= sz) return;
  int bnd = 144*xcd + 64 - 64*(xcd == 0) - 16*(xcd == 1) + 16*(xcd == 7);
  int logical = bnd + idx;                       // 0..1279
  int l = logical >> 8;
  int rem = logical & 255;
  int n0 = (rem >> 2) * 128;
  int e0 = (rem & 3) * 128;
  int b = n0 >> 10;

  __shared__ char As[16384];
  __shared__ char Bs[16384];
  int tid = threadIdx.x, lane = tid & 63;
  int wbu = __builtin_amdgcn_readfirstlane(tid & ~63);
  int w = wbu >> 6, wr = w & 1, wc = w >> 1, lo = lane & 15, g = lane >> 4;
  const float* denom = denomCyc + (size_t)l*1024;
  f32x4 acc[4][4] = {};
  // PV first, then scale by w4/denom in registers
  gemm128(PAll + (size_t)l*SEs + (size_t)n0*PP, PP,
          XbfTAll + (size_t)l*NEs + (size_t)b*EE*PP + (size_t)e0*PP, PP, 16,
          As, Bs, wbu, lane, acc);
  float w4 = *w4p;
#pragma unroll
  for (int m = 0; m < 4; ++m)
#pragma unroll
    for (int r = 0; r < 4; ++r) {
      int q = (n0 + wr*64 + m*16 + g*4 + r) & 1023;
      float s = w4 / denom[q];
#pragma unroll
      for (int n = 0; n < 4; ++n) acc[m][n][r] *= s;
    }
  if (l > 0)
    gemm128(BpostAll + (size_t)(l-1)*NEs + (size_t)n0*EE, EE,
            WbuAll + (size_t)l*EE*EE + (size_t)e0*EE, EE, 8, As, Bs, wbu, lane, acc);
  if (l < 4)
    gemm128(BpreCur + (size_t)(l+1)*NEs + (size_t)n0*EE, EE,
            WtdAll + (size_t)l*EE*EE + (size_t)e0*EE, EE, 8, As, Bs, wbu, lane, acc);
  float w1 = *w1p;
  const u16* Xh = BpostAll + (size_t)l*NEs;
  const u16* Lc = LcAll + (size_t)l*PEs;
  u16* Obf = BpreNext + (size_t)l*NEs;
  float stS[4] = {}, stQ[4] = {};
#pragma unroll
  for (int m = 0; m < 4; ++m)
#pragma unroll
    for (int n = 0; n < 4; ++n)
#pragma unroll
      for (int r = 0; r < 4; ++r) {
        int nn = n0 + wr*64 + m*16 + g*4 + r;
        int e = e0 + wc*64 + n*16 + lo;
        size_t idx2 = (size_t)nn*EE + e;
        float v = acc[m][n][r] + w1*bf2f(Xh[idx2]) + bf2f(Lc[(size_t)(nn & 1023)*EE + e]);
        Obf[idx2] = f2bf(v);
        if (ACCST) { stS[n] += v; stQ[n] += v*v; }
      }
  if (ACCST) {
#pragma unroll
    for (int n = 0; n < 4; ++n) {
      float s = stS[n], q2 = stQ[n];
      s  += __shfl_xor(s, 16);  s  += __shfl_xor(s, 32);
      q2 += __shfl_xor(q2, 16); q2 += __shfl_xor(q2, 32);
      if (g == 0) {
        int e = e0 + wc*64 + n*16 + lo;
        atomicAdd(&statsB[(size_t)l*1024 + e], s);
        atomicAdd(&statsB[(size_t)l*1024 + EE + e], q2);
      }
    }
  }
}

// ---- final transpose: Bpre bf16 [l][b][hw][e] -> out f32 [b][e][hw][5] -----
__global__ __launch_bounds__(256) void k_transpose_bf(const u16* __restrict__ Bpre,
                                                      float* __restrict__ out) {
  __shared__ u16 tile[5][32][34];
  int t = threadIdx.x;
  int hw0 = blockIdx.x * 32, e0 = blockIdx.y * 32, b = blockIdx.z;
  int tr = t >> 5, tc = t & 31;
#pragma unroll
  for (int l = 0; l < 5; ++l) {
    const u16* src = Bpre + (size_t)l*NEs + ((size_t)(b*PP + hw0))*EE + e0;
    for (int p = 0; p < 4; ++p)
      tile[l][tr + 8*p][tc] = src[(size_t)(tr + 8*p)*EE + tc];
  }
  __syncthreads();
  for (int p = 0; p < 4; ++p) {
    int e = tr + 8*p;
    float* dst = out + (((size_t)(b*EE + e0 + e))*PP + (size_t)(hw0 + tc))*5;
#pragma unroll
    for (int l = 0; l < 5; ++l) dst[l] = bf2f(tile[l][tc][e]);
  }
}

// ---------------------------------------------------------------------------
extern "C" void kernel_launch(void* const* d_in, const int* in_sizes, int n_in,
                              void* d_out, int out_size, void* d_ws, size_t ws_size,
                              hipStream_t stream) {
  const float* x     = (const float*)d_in[0];
  const float* convw = (const float*)d_in[1];
  const float* convb = (const float*)d_in[2];
  const float* bu_w  = (const float*)d_in[3];
  const float* bu_b  = (const float*)d_in[4];
  const float* td_w  = (const float*)d_in[5];
  const float* td_b  = (const float*)d_in[6];
  const float* bn_g  = (const float*)d_in[7];
  const float* bn_b  = (const float*)d_in[8];
  const float* w1 = (const float*)d_in[9];
  const float* w2 = (const float*)d_in[10];
  const float* w3 = (const float*)d_in[11];
  const float* w4 = (const float*)d_in[12];
  float* out = (float*)d_out;

  // ws layout (u16 units unless noted); total ~266 MB
  u16* BpreA  = (u16*)d_ws;                    // 5*NE  cycle-0 in / cycle-1 out
  u16* BpreB  = BpreA + 5*NEs;                 // 5*NE  cycle-0 out / cycle-1 in
  u16* BpostA = BpreB + 5*NEs;                 // 5*NE  post-BN (all levels)
  u16* XbfTA  = BpostA + 5*NEs;                // 5*NE  transposed post-BN
  u16* PAll   = XbfTA + 5*NEs;                 // 5*SEs P matrices
  u16* Lcomb  = PAll + 5*SEs;                  // 5*PE
  u16* Wbu_s  = Lcomb + 5*PEs;                 // 5*512*512
  u16* Wtd_s  = Wbu_s + (size_t)5*EE*EE;       // 5*512*512
  u16* Apat   = Wtd_s + (size_t)5*EE*EE;       // 8192*192
  u16* Wcv    = Apat + (size_t)NT*KC;          // 512*192
  float* locb   = (float*)(Wcv + (size_t)EE*KC);   // 40960 f32
  float* Wcomb  = locb + 40960;                // 5*40*512
  float* bcomb  = Wcomb + 102400;              // 2560
  float* statsA = bcomb + 2560;                // 5*1024
  float* statsB = statsA + 5*1024;             // 5*1024
  float* denomAll = statsB + 5*1024;           // 10*1024

  // ---- setup ----
  k_locb<<<4, 256, 0, stream>>>(locb);
  k_wcombT<<<dim3(5, 8), 256, 0, stream>>>(bu_w, bu_b, td_w, td_b, w2, w3, Wcomb, bcomb);
  k_loccomb2<<<dim3(5, 64), 256, 0, stream>>>(locb, Wcomb, bcomb, Lcomb);
  k_wconv<<<dim3(640, 2), 256, 0, stream>>>(bu_w, td_w, w2, w3, Wbu_s, Wtd_s);
  k_wcv<<<48, 256, 0, stream>>>(convw, Wcv);
  k_im2col<<<768, 256, 0, stream>>>(x, Apat);
  hipMemsetAsync(BpreA + NEs, 0, 4*NEs*sizeof(u16), stream);   // levels 1..4 zero
  hipMemsetAsync(statsA, 0, (5*1024 + 5*1024 + 10*1024)*sizeof(float), stream);
  k_cgemm<<<dim3(64, 4), 256, 0, stream>>>(Apat, Wcv, convb, BpreA, statsA);

  for (int cyc = 0; cyc < 2; ++cyc) {
    u16* BpreCur  = (cyc == 0) ? BpreA : BpreB;
    u16* BpreNext = (cyc == 0) ? BpreB : BpreA;
    const float* statsSel = (cyc == 0) ? statsA : statsB;
    float* denomCyc = denomAll + (size_t)cyc*5*1024;
    k_bnx<<<dim3(32,16,40), 256, 0, stream>>>(BpreCur, statsSel, bn_g, bn_b,
                                              BpostA, XbfTA);
    k_gemm1<<<1440, 256, 0, stream>>>(BpostA, PAll, denomCyc);
    if (cyc == 0)
      k_mega<1><<<1536, 256, 0, stream>>>(BpostA, BpreCur, PAll, XbfTA,
          Wbu_s, Wtd_s, Lcomb, w1, w4, denomCyc, statsB, BpreNext);
    else
      k_mega<0><<<1536, 256, 0, stream>>>(BpostA, BpreCur, PAll, XbfTA,
          Wbu_s, Wtd_s, Lcomb, w1, w4, denomCyc, nullptr, BpreNext);
  }
  k_transpose_bf<<<dim3(32,16,8), 256, 0, stream>>>(BpreA, out);
}